// Round 13
// baseline (216.453 us; speedup 1.0000x reference)
//
#include <hip/hip_runtime.h>

typedef unsigned short u16;
typedef unsigned int   u32;
typedef __bf16 bf16x8 __attribute__((ext_vector_type(8)));
typedef float  f32x4  __attribute__((ext_vector_type(4)));
typedef float  f32x16 __attribute__((ext_vector_type(16)));

union U16B { int4 i4; bf16x8 b8; u16 u[8]; };
union U16Q { uint2 d2; u16 u[4]; };
union PK2  { u32 w; __bf16 b[2]; };
union BF8W { u32 w[4]; bf16x8 v; };

static __device__ __forceinline__ u16 f2b(float f) {
  u32 x = __float_as_uint(f);
  x += 0x7FFFu + ((x >> 16) & 1u);   // RNE (inputs finite)
  return (u16)(x >> 16);
}
static __device__ __forceinline__ float b2f(u16 s) {
  return __uint_as_float(((u32)s) << 16);
}
static __device__ __forceinline__ u32 pk2(float a, float b) {
  PK2 p; p.b[0] = (__bf16)a; p.b[1] = (__bf16)b; return p.w;
}

// async global->LDS: dest must be linear (wave-uniform base + lane*16)
#define GLOAD_LDS16(g, l) \
  __builtin_amdgcn_global_load_lds((const __attribute__((address_space(1))) u32*)(g), \
                                   (__attribute__((address_space(3))) u32*)(l), 16, 0, 0)

// ---------------- fp32 -> bf16 convert (inputs, once) ----------------
struct ConvA { const float* src[3]; u16* dst[3]; };

__global__ __launch_bounds__(256) void convA(ConvA a) {
  const float* s = a.src[blockIdx.z];
  u16*         d = a.dst[blockIdx.z];
  const size_t i = ((size_t)blockIdx.x * 256 + threadIdx.x) * 8;
  float4 f0 = *(const float4*)(s + i);
  float4 f1 = *(const float4*)(s + i + 4);
  U16B t;
  t.u[0] = f2b(f0.x); t.u[1] = f2b(f0.y); t.u[2] = f2b(f0.z); t.u[3] = f2b(f0.w);
  t.u[4] = f2b(f1.x); t.u[5] = f2b(f1.y); t.u[6] = f2b(f1.z); t.u[7] = f2b(f1.w);
  *(int4*)(d + i) = t.i4;
}

// ---------------- weight transpose + fp32->bf16 convert ----------------
struct TransA { const float* W[4]; u16* Wt[4]; };

__global__ __launch_bounds__(256) void transW(TransA a) {
  const float* W  = a.W[blockIdx.z];
  u16*         Wt = a.Wt[blockIdx.z];
  __shared__ float t[64][65];
  const int bx = blockIdx.x * 64, by = blockIdx.y * 64;
  const int tx = threadIdx.x & 63, ty = threadIdx.x >> 6;
  #pragma unroll
  for (int j = 0; j < 16; ++j) {
    int row = j * 4 + ty;
    t[row][tx] = W[(size_t)(by + row) * 1024 + bx + tx];
  }
  __syncthreads();
  #pragma unroll
  for (int j = 0; j < 16; ++j) {
    int row = j * 4 + ty;           // Wt[n][k] = W[k][n]
    Wt[(size_t)(bx + row) * 1024 + by + tx] = f2b(t[tx][row]);
  }
}

// ---------------- GEMM: C = A[M][K](bf16) * Bt[N][K]^T + bias ----------------
// 128x128 tile, BK=64, 4 waves, m97 2-barrier structure, global_load_lds
// staging (linear dest, pre-swizzled source; rule #21). Unchanged from R7-R11.
struct GemmB { const u16* A[3]; const u16* Bt[3]; const float* bias[3]; void* C[3]; int mode[3]; int cpx; };

__global__ __launch_bounds__(256) void gemm_bt(GemmB g) {
  constexpr int K = 1024, N = 1024;
  __shared__ u16 As[128 * 64];
  __shared__ u16 Bs[128 * 64];
  const int bid = blockIdx.x;
  const int lg = (bid & 7) * g.cpx + (bid >> 3);
  const int z = lg >> 8;
  const int rem = lg & 255;
  const int row0 = (rem >> 3) * 128, col0 = (rem & 7) * 128;
  const u16*   Ap   = g.A[z];
  const u16*   Bt   = g.Bt[z];
  const float* bias = g.bias[z];
  const int mode = g.mode[z];
  const int tid = threadIdx.x;
  const int wid = tid >> 6, lane = tid & 63;
  const int wr = wid >> 1, wc = wid & 1;
  const int lo = lane & 15, hi = lane >> 4;
  const int rs = tid >> 3, us = tid & 7;
  const int sw = (us ^ (rs & 7)) * 8;   // pre-swizzled source column unit

  f32x4 acc[4][4];
  const f32x4 z4 = {0.f, 0.f, 0.f, 0.f};
  #pragma unroll
  for (int i = 0; i < 4; ++i)
    #pragma unroll
    for (int j = 0; j < 4; ++j) acc[i][j] = z4;

  for (int kt = 0; kt < K / 64; ++kt) {
    __syncthreads();
    #pragma unroll
    for (int c = 0; c < 4; ++c) {
      int r = c * 32 + rs;
      GLOAD_LDS16(Ap + (size_t)(row0 + r) * K + kt * 64 + sw, &As[r * 64 + us * 8]);
      GLOAD_LDS16(Bt + (size_t)(col0 + r) * K + kt * 64 + sw, &Bs[r * 64 + us * 8]);
    }
    __syncthreads();   // compiler drains vmcnt before s_barrier
    #pragma unroll
    for (int ks = 0; ks < 2; ++ks) {
      bf16x8 af[4], bfr[4];
      #pragma unroll
      for (int mf = 0; mf < 4; ++mf) {
        int r = wr * 64 + mf * 16 + lo;
        af[mf] = *(const bf16x8*)&As[r * 64 + (((ks * 4 + hi) ^ (r & 7)) << 3)];
      }
      #pragma unroll
      for (int nf = 0; nf < 4; ++nf) {
        int r = wc * 64 + nf * 16 + lo;
        bfr[nf] = *(const bf16x8*)&Bs[r * 64 + (((ks * 4 + hi) ^ (r & 7)) << 3)];
      }
      #pragma unroll
      for (int mf = 0; mf < 4; ++mf)
        #pragma unroll
        for (int nf = 0; nf < 4; ++nf)
          acc[mf][nf] = __builtin_amdgcn_mfma_f32_16x16x32_bf16(af[mf], bfr[nf], acc[mf][nf], 0, 0, 0);
    }
  }

  #pragma unroll
  for (int nf = 0; nf < 4; ++nf) {
    int col = col0 + wc * 64 + nf * 16 + lo;
    float bv = bias[col];
    #pragma unroll
    for (int mf = 0; mf < 4; ++mf) {
      int rb = row0 + wr * 64 + mf * 16 + hi * 4;   // C/D: row=(l>>4)*4+e, col=l&15
      if (mode == 2) {
        U16Q q4;
        #pragma unroll
        for (int e = 0; e < 4; ++e) q4.u[e] = f2b(acc[mf][nf][e] + bv);
        *(uint2*)&((u16*)g.C[z])[(size_t)col * 4096 + rb] = q4.d2;   // C^T[N][4096]
      } else {
        #pragma unroll
        for (int e = 0; e < 4; ++e) {
          float v = acc[mf][nf][e] + bv;
          if (mode == 1) ((float*)g.C[z])[(size_t)(rb + e) * N + col] = v;
          else           ((u16*)g.C[z])[(size_t)(rb + e) * N + col] = f2b(v);
        }
      }
    }
  }
}

// ---------------- flash attention: BARRIER-FREE, K/V direct from L2 ----------------
// R8-R11 ablations: staging latency, occupancy, LDS traffic, softmax machinery
// all null at ~80us -> the invariant wall is the barriered LDS-staging skeleton
// itself (stage -> vmcnt(0) drain -> barrier -> lockstep; m233's 2-phase stall).
// This kernel deletes it: NO barriers, NO K/V LDS. Each wave reads its MFMA K/V
// fragments directly from global (L2-resident; VpT pre-transposed so PV's
// A-operand is contiguous). Body = R11's numerically-validated 32x32 in-register
// softmax (swapped QK^T -> lane owns q=lane&31; P^T built via cvt-pack + 1
// shfl_xor(32) exchange; per-lane rescale). Swizzle cancels in the LDS->global
// address translation: Ks[lq][u^swz^swz] == K[kv0+lq][u*8].
// Split-KV x2 (R9's validated combine) restores wave count: 4096 waves = 4/SIMD.
// LDS: only 4KB/wave private epilogue transpose (same-wave pattern, no barrier).
__global__ __launch_bounds__(256) void attn_fwd(const u16* __restrict__ Q,
                                                const u16* __restrict__ Kp,
                                                const u16* __restrict__ VpT,
                                                u16* __restrict__ Part,
                                                float2* __restrict__ St) {
  __shared__ u16 tb[4 * 2048];               // 4 waves x 4KB epilogue transpose
  const int tid = threadIdx.x;
  const int bid = blockIdx.x;                // xcd=bid&7 owns 4 hb (L2 locality)
  const int t = bid >> 3;                    // [0,128)
  const int hb = (bid & 7) * 4 + (t >> 5);   // [0,32)
  const int rem = t & 31;
  const int qb = rem >> 1;                   // [0,16) : 128 q-rows each
  const int split = rem & 1;
  const int h = hb & 15, b = hb >> 4;
  const int wid = tid >> 6, lane = tid & 63;
  const int lq = lane & 31;                  // q (and matrix row/col) index
  const int hh = lane >> 5;                  // wave half
  const int hoff = h * 64;
  const size_t rowQ0 = (size_t)b * 2048 + (size_t)qb * 128;
  const int woff = wid * 32;
  const float QSCALE = 0.125f * 1.4426950408889634f;
  const int kb0 = split * 16;

  // Q fragments (B-operand): lane holds Q[q=lq][d = ds*16 + hh*8 + j], scaled
  bf16x8 qf[4];
  #pragma unroll
  for (int ds = 0; ds < 4; ++ds) {
    size_t r = rowQ0 + woff + lq;
    U16B in; in.i4 = *(const int4*)&Q[r * 1024 + hoff + ds * 16 + hh * 8];
    U16B o;
    #pragma unroll
    for (int j = 0; j < 8; ++j) o.u[j] = f2b(b2f(in.u[j]) * QSCALE);
    qf[ds] = o.b8;
  }

  f32x16 oacc[2];
  #pragma unroll
  for (int dt = 0; dt < 2; ++dt)
    #pragma unroll
    for (int r = 0; r < 16; ++r) oacc[dt][r] = 0.f;
  float m_r = -1e30f, l_r = 0.f;   // stats for q=lq (identical in both halves)

  const u16* kBase  = Kp + ((size_t)b * 2048 + lq) * 1024 + hoff;     // + kv0*1024 (+32*1024)
  const u16* vBase0 = VpT + (size_t)(hoff + lq) * 4096 + b * 2048;    // + kv0  (dt=0)
  const u16* vBase1 = vBase0 + (size_t)32 * 4096;                     //        (dt=1)

  for (int kb = 0; kb < 16; ++kb) {
    const int kv0 = (kb0 + kb) * 64;
    const u16* kA = kBase + (size_t)kv0 * 1024;
    const u16* kB = kA + 32 * 1024;

    // S^T = K Q^T (two 32x32 subtiles). Lane: q=lq, kk=(r&3)+8(r>>2)+4hh
    f32x16 s0, s1;
    #pragma unroll
    for (int r = 0; r < 16; ++r) { s0[r] = 0.f; s1[r] = 0.f; }
    #pragma unroll
    for (int ds = 0; ds < 4; ++ds) {
      int u8 = (2 * ds + hh) * 8;
      bf16x8 k0 = *(const bf16x8*)(kA + u8);
      bf16x8 k1 = *(const bf16x8*)(kB + u8);
      s0 = __builtin_amdgcn_mfma_f32_32x32x16_bf16(k0, qf[ds], s0, 0, 0, 0);
      s1 = __builtin_amdgcn_mfma_f32_32x32x16_bf16(k1, qf[ds], s1, 0, 0, 0);
    }

    // online softmax, fully in-register (row q = lq)
    float pm = -1e30f;
    #pragma unroll
    for (int r = 0; r < 16; ++r) pm = fmaxf(pm, fmaxf(s0[r], s1[r]));
    pm = fmaxf(pm, __shfl_xor(pm, 32));
    float mn = fmaxf(m_r, pm);
    float cc = __builtin_amdgcn_exp2f(m_r - mn);
    m_r = mn;
    #pragma unroll
    for (int dt = 0; dt < 2; ++dt)
      #pragma unroll
      for (int r = 0; r < 16; ++r) oacc[dt][r] *= cc;
    float ps = 0.f;
    u32 c[16];
    #pragma unroll
    for (int m = 0; m < 8; ++m) {
      float e0 = __builtin_amdgcn_exp2f(s0[2 * m] - mn);
      float e1 = __builtin_amdgcn_exp2f(s0[2 * m + 1] - mn);
      ps += e0 + e1;
      c[m] = pk2(e0, e1);
    }
    #pragma unroll
    for (int m = 0; m < 8; ++m) {
      float e0 = __builtin_amdgcn_exp2f(s1[2 * m] - mn);
      float e1 = __builtin_amdgcn_exp2f(s1[2 * m + 1] - mn);
      ps += e0 + e1;
      c[8 + m] = pk2(e0, e1);
    }
    ps += __shfl_xor(ps, 32);
    l_r = l_r * cc + ps;

    // exchange halves: x[m] = lane^32's c[m]
    u32 x[16];
    #pragma unroll
    for (int m = 0; m < 16; ++m) x[m] = (u32)__shfl_xor((int)c[m], 32);

    // PV: O^T += V^T P^T  (A = V^T direct from global, B = P^T from c/x)
    #pragma unroll
    for (int sub = 0; sub < 2; ++sub) {
      const int cb = sub * 8;
      #pragma unroll
      for (int ksp = 0; ksp < 2; ++ksp) {
        BF8W bw;
        if (ksp == 0) {
          bw.w[0] = hh ? x[cb + 2] : c[cb + 0];
          bw.w[1] = hh ? x[cb + 3] : c[cb + 1];
          bw.w[2] = hh ? c[cb + 2] : x[cb + 0];
          bw.w[3] = hh ? c[cb + 3] : x[cb + 1];
        } else {
          bw.w[0] = hh ? x[cb + 6] : c[cb + 4];
          bw.w[1] = hh ? x[cb + 7] : c[cb + 5];
          bw.w[2] = hh ? c[cb + 6] : x[cb + 4];
          bw.w[3] = hh ? c[cb + 7] : x[cb + 5];
        }
        int u8 = (4 * sub + 2 * ksp + hh) * 8;
        bf16x8 va0 = *(const bf16x8*)(vBase0 + kv0 + u8);
        bf16x8 va1 = *(const bf16x8*)(vBase1 + kv0 + u8);
        oacc[0] = __builtin_amdgcn_mfma_f32_32x32x16_bf16(va0, bw.v, oacc[0], 0, 0, 0);
        oacc[1] = __builtin_amdgcn_mfma_f32_32x32x16_bf16(va1, bw.v, oacc[1], 0, 0, 0);
      }
    }
  }

  // epilogue: UNNORMALIZED partial; transpose O^T -> O via per-wave LDS buffer
  // (same-wave ds_write -> ds_read, compiler-ordered; validated in R11)
  u16* wreg = tb + wid * 2048;
  #pragma unroll
  for (int dt = 0; dt < 2; ++dt)
    #pragma unroll
    for (int m = 0; m < 8; ++m) {
      int bcol = ((2 * m) & 3) + 8 * (m >> 1) + 4 * hh + 32 * dt;   // d of pair
      u32 pw = pk2(oacc[dt][2 * m], oacc[dt][2 * m + 1]);
      char* p = (char*)wreg + lq * 128 + (((bcol >> 3) ^ (lq & 7)) << 4) + (bcol & 7) * 2;
      *(u32*)p = pw;
    }
  u16* Po = Part + (size_t)split * 4096 * 1024;
  #pragma unroll
  for (int pss = 0; pss < 4; ++pss) {
    int q = pss * 8 + (lane >> 3);
    int u = lane & 7;
    int4 v = *(const int4*)((const char*)wreg + q * 128 + ((u ^ (q & 7)) << 4));
    *(int4*)&Po[(rowQ0 + woff + q) * 1024 + hoff + u * 8] = v;
  }
  if (hh == 0) {   // stats for q=lq (hh replicas identical)
    size_t qg = (size_t)qb * 128 + woff + lq;
    St[((size_t)(split * 2 + b) * 16 + h) * 2048 + qg] = make_float2(m_r, l_r);
  }
}

// ---------------- combine the two KV-splits (validated R9) ----------------
__global__ __launch_bounds__(256) void attn_combine(const u16* __restrict__ Part,
                                                    const float2* __restrict__ St,
                                                    u16* __restrict__ Op) {
  const size_t i = ((size_t)blockIdx.x * 256 + threadIdx.x) * 8;
  const int row = (int)(i >> 10);        // [0,4096)
  const int col = (int)(i & 1023);
  const int h = col >> 6;
  const int b = row >> 11, q = row & 2047;
  const float2 s0 = St[((size_t)(0 + b) * 16 + h) * 2048 + q];
  const float2 s1 = St[((size_t)(2 + b) * 16 + h) * 2048 + q];
  const float m = fmaxf(s0.x, s1.x);
  float w0 = __builtin_amdgcn_exp2f(s0.x - m);
  float w1 = __builtin_amdgcn_exp2f(s1.x - m);
  const float inv = __builtin_amdgcn_rcpf(w0 * s0.y + w1 * s1.y);
  w0 *= inv; w1 *= inv;
  U16B p0, p1, o;
  p0.i4 = *(const int4*)(Part + i);
  p1.i4 = *(const int4*)(Part + (size_t)4096 * 1024 + i);
  #pragma unroll
  for (int j = 0; j < 8; ++j)
    o.u[j] = f2b(w0 * b2f(p0.u[j]) + w1 * b2f(p1.u[j]));
  *(int4*)(Op + i) = o.i4;
}

// ---------------- launch ----------------
extern "C" void kernel_launch(void* const* d_in, const int* in_sizes, int n_in,
                              void* d_out, int out_size, void* d_ws, size_t ws_size,
                              hipStream_t stream) {
  (void)in_sizes; (void)n_in; (void)out_size;
  const size_t MB = 1024 * 1024;
  if (ws_size < 40 * MB) return;
  char* ws = (char*)d_ws;
  u16* Wqt = (u16*)(ws + 0 * MB);
  u16* Wkt = (u16*)(ws + 2 * MB);
  u16* Wvt = (u16*)(ws + 4 * MB);
  u16* Wot = (u16*)(ws + 6 * MB);
  u16* Vb  = (u16*)(ws + 8 * MB);    // bf16 value-input; later reused as Op
  u16* Qp  = (u16*)(ws + 16 * MB);
  u16* Kp  = (u16*)(ws + 24 * MB);
  u16* VpT = (u16*)(ws + 32 * MB);   // V^T [1024][4096]
  u16* Op  = (u16*)(ws + 8 * MB);    // reuse Vb space (dead after QKV GEMM)
  float2* St = (float2*)(ws + 0 * MB);      // attn stats: 2MB in dead Wqt region
  // bf16 query/key inputs parked in d_out (16MB; dead after QKV GEMM).
  // Then d_out holds attn O-partials (dead after combine), then final f32 out.
  u16* Qb = (u16*)d_out;
  u16* Kb = (u16*)d_out + (size_t)4 * MB;   // element offset: 8MB bytes
  u16* Part = (u16*)d_out;                  // 2 x 8MB bf16 O-partials

  ConvA ca;
  ca.src[0] = (const float*)d_in[0]; ca.dst[0] = Qb;
  ca.src[1] = (const float*)d_in[1]; ca.dst[1] = Kb;
  ca.src[2] = (const float*)d_in[2]; ca.dst[2] = Vb;
  hipLaunchKernelGGL(convA, dim3(2048, 1, 3), dim3(256), 0, stream, ca);

  TransA ta;
  ta.W[0] = (const float*)d_in[3]; ta.Wt[0] = Wqt;
  ta.W[1] = (const float*)d_in[5]; ta.Wt[1] = Wkt;
  ta.W[2] = (const float*)d_in[7]; ta.Wt[2] = Wvt;
  ta.W[3] = (const float*)d_in[9]; ta.Wt[3] = Wot;
  hipLaunchKernelGGL(transW, dim3(16, 16, 4), dim3(256), 0, stream, ta);

  GemmB gp;
  gp.A[0] = Qb; gp.Bt[0] = Wqt; gp.bias[0] = (const float*)d_in[4]; gp.C[0] = Qp;  gp.mode[0] = 0;
  gp.A[1] = Kb; gp.Bt[1] = Wkt; gp.bias[1] = (const float*)d_in[6]; gp.C[1] = Kp;  gp.mode[1] = 0;
  gp.A[2] = Vb; gp.Bt[2] = Wvt; gp.bias[2] = (const float*)d_in[8]; gp.C[2] = VpT; gp.mode[2] = 2;
  gp.cpx = 96;
  hipLaunchKernelGGL(gemm_bt, dim3(768), dim3(256), 0, stream, gp);

  hipLaunchKernelGGL(attn_fwd, dim3(1024), dim3(256), 0, stream, Qp, Kp, VpT, Part, St);
  hipLaunchKernelGGL(attn_combine, dim3(2048), dim3(256), 0, stream, Part, St, Op);

  GemmB gf;
  gf.A[0] = Op; gf.Bt[0] = Wot; gf.bias[0] = (const float*)d_in[10]; gf.C[0] = (void*)d_out; gf.mode[0] = 1;
  gf.A[1] = nullptr; gf.A[2] = nullptr; gf.Bt[1] = nullptr; gf.Bt[2] = nullptr;
  gf.bias[1] = nullptr; gf.bias[2] = nullptr; gf.C[1] = nullptr; gf.C[2] = nullptr;
  gf.mode[1] = 0; gf.mode[2] = 0;
  gf.cpx = 32;
  hipLaunchKernelGGL(gemm_bt, dim3(256), dim3(256), 0, stream, gf);
}

// Round 14
// 153.832 us; speedup vs baseline: 1.4071x; 1.4071x over previous
//
#include <hip/hip_runtime.h>

typedef unsigned short u16;
typedef unsigned int   u32;
typedef __bf16 bf16x8 __attribute__((ext_vector_type(8)));
typedef float  f32x4  __attribute__((ext_vector_type(4)));

union U16B { int4 i4; bf16x8 b8; u16 u[8]; };
union U16Q { uint2 d2; u16 u[4]; };
union PK4  { uint2 d2; __bf16 b[4]; };

static __device__ __forceinline__ u16 f2b(float f) {
  u32 x = __float_as_uint(f);
  x += 0x7FFFu + ((x >> 16) & 1u);   // RNE (inputs finite)
  return (u16)(x >> 16);
}
static __device__ __forceinline__ float b2f(u16 s) {
  return __uint_as_float(((u32)s) << 16);
}

// async global->LDS: dest must be linear (wave-uniform base + lane*16)
#define GLOAD_LDS16(g, l) \
  __builtin_amdgcn_global_load_lds((const __attribute__((address_space(1))) u32*)(g), \
                                   (__attribute__((address_space(3))) u32*)(l), 16, 0, 0)

// ---------------- fp32 -> bf16 convert (inputs, once) ----------------
struct ConvA { const float* src[3]; u16* dst[3]; };

__global__ __launch_bounds__(256) void convA(ConvA a) {
  const float* s = a.src[blockIdx.z];
  u16*         d = a.dst[blockIdx.z];
  const size_t i = ((size_t)blockIdx.x * 256 + threadIdx.x) * 8;
  float4 f0 = *(const float4*)(s + i);
  float4 f1 = *(const float4*)(s + i + 4);
  U16B t;
  t.u[0] = f2b(f0.x); t.u[1] = f2b(f0.y); t.u[2] = f2b(f0.z); t.u[3] = f2b(f0.w);
  t.u[4] = f2b(f1.x); t.u[5] = f2b(f1.y); t.u[6] = f2b(f1.z); t.u[7] = f2b(f1.w);
  *(int4*)(d + i) = t.i4;
}

// ---------------- weight transpose + fp32->bf16 convert ----------------
struct TransA { const float* W[4]; u16* Wt[4]; };

__global__ __launch_bounds__(256) void transW(TransA a) {
  const float* W  = a.W[blockIdx.z];
  u16*         Wt = a.Wt[blockIdx.z];
  __shared__ float t[64][65];
  const int bx = blockIdx.x * 64, by = blockIdx.y * 64;
  const int tx = threadIdx.x & 63, ty = threadIdx.x >> 6;
  #pragma unroll
  for (int j = 0; j < 16; ++j) {
    int row = j * 4 + ty;
    t[row][tx] = W[(size_t)(by + row) * 1024 + bx + tx];
  }
  __syncthreads();
  #pragma unroll
  for (int j = 0; j < 16; ++j) {
    int row = j * 4 + ty;           // Wt[n][k] = W[k][n]
    Wt[(size_t)(bx + row) * 1024 + by + tx] = f2b(t[tx][row]);
  }
}

// ---------------- GEMM: C = A[M][K](bf16) * Bt[N][K]^T + bias ----------------
// 128x128 tile, BK=64, 4 waves, m97 2-barrier structure, global_load_lds
// staging (linear dest, pre-swizzled source; rule #21). Unchanged from R7/R8.
struct GemmB { const u16* A[3]; const u16* Bt[3]; const float* bias[3]; void* C[3]; int mode[3]; int cpx; };

__global__ __launch_bounds__(256) void gemm_bt(GemmB g) {
  constexpr int K = 1024, N = 1024;
  __shared__ u16 As[128 * 64];
  __shared__ u16 Bs[128 * 64];
  const int bid = blockIdx.x;
  const int lg = (bid & 7) * g.cpx + (bid >> 3);
  const int z = lg >> 8;
  const int rem = lg & 255;
  const int row0 = (rem >> 3) * 128, col0 = (rem & 7) * 128;
  const u16*   Ap   = g.A[z];
  const u16*   Bt   = g.Bt[z];
  const float* bias = g.bias[z];
  const int mode = g.mode[z];
  const int tid = threadIdx.x;
  const int wid = tid >> 6, lane = tid & 63;
  const int wr = wid >> 1, wc = wid & 1;
  const int lo = lane & 15, hi = lane >> 4;
  const int rs = tid >> 3, us = tid & 7;
  const int sw = (us ^ (rs & 7)) * 8;   // pre-swizzled source column unit

  f32x4 acc[4][4];
  const f32x4 z4 = {0.f, 0.f, 0.f, 0.f};
  #pragma unroll
  for (int i = 0; i < 4; ++i)
    #pragma unroll
    for (int j = 0; j < 4; ++j) acc[i][j] = z4;

  for (int kt = 0; kt < K / 64; ++kt) {
    __syncthreads();
    #pragma unroll
    for (int c = 0; c < 4; ++c) {
      int r = c * 32 + rs;
      GLOAD_LDS16(Ap + (size_t)(row0 + r) * K + kt * 64 + sw, &As[r * 64 + us * 8]);
      GLOAD_LDS16(Bt + (size_t)(col0 + r) * K + kt * 64 + sw, &Bs[r * 64 + us * 8]);
    }
    __syncthreads();   // compiler drains vmcnt before s_barrier
    #pragma unroll
    for (int ks = 0; ks < 2; ++ks) {
      bf16x8 af[4], bfr[4];
      #pragma unroll
      for (int mf = 0; mf < 4; ++mf) {
        int r = wr * 64 + mf * 16 + lo;
        af[mf] = *(const bf16x8*)&As[r * 64 + (((ks * 4 + hi) ^ (r & 7)) << 3)];
      }
      #pragma unroll
      for (int nf = 0; nf < 4; ++nf) {
        int r = wc * 64 + nf * 16 + lo;
        bfr[nf] = *(const bf16x8*)&Bs[r * 64 + (((ks * 4 + hi) ^ (r & 7)) << 3)];
      }
      #pragma unroll
      for (int mf = 0; mf < 4; ++mf)
        #pragma unroll
        for (int nf = 0; nf < 4; ++nf)
          acc[mf][nf] = __builtin_amdgcn_mfma_f32_16x16x32_bf16(af[mf], bfr[nf], acc[mf][nf], 0, 0, 0);
    }
  }

  #pragma unroll
  for (int nf = 0; nf < 4; ++nf) {
    int col = col0 + wc * 64 + nf * 16 + lo;
    float bv = bias[col];
    #pragma unroll
    for (int mf = 0; mf < 4; ++mf) {
      int rb = row0 + wr * 64 + mf * 16 + hi * 4;   // C/D: row=(l>>4)*4+e, col=l&15
      if (mode == 2) {
        U16Q q4;
        #pragma unroll
        for (int e = 0; e < 4; ++e) q4.u[e] = f2b(acc[mf][nf][e] + bv);
        *(uint2*)&((u16*)g.C[z])[(size_t)col * 4096 + rb] = q4.d2;   // C^T[N][4096]
      } else {
        #pragma unroll
        for (int e = 0; e < 4; ++e) {
          float v = acc[mf][nf][e] + bv;
          if (mode == 1) ((float*)g.C[z])[(size_t)(rb + e) * N + col] = v;
          else           ((u16*)g.C[z])[(size_t)(rb + e) * N + col] = f2b(v);
        }
      }
    }
  }
}

// ---------------- flash attention ----------------
// R8 structure (best measured: attn 79.4us, VGPR=60, WRITE=8MB): dbuf K/V via
// global_load_lds (zero regs across barriers), ONE barrier/iter. ONE change:
// defer-max THR=8 (T13) — skip rescale machinery (1 exp2 + 16 muls + 4
// bpermutes + l mul) unless the tile max grows by >8 (log2 domain; P <= 2^8,
// safe in f32 accum / bf16 pack). Also max-reduce as fmax triples (v_max3).
// R5's spill suspects were {early-issue regs, defer-max}; this isolates
// defer-max on the clean gload_lds base (sentinels: VGPR, WRITE_SIZE).
__global__ __launch_bounds__(256) void attn_fwd(const u16* __restrict__ Q,
                                                const u16* __restrict__ Kp,
                                                const u16* __restrict__ VpT,
                                                u16* __restrict__ O) {
  __shared__ u16 Ks[2][64 * 64];    // K tiles [kk][d], XOR-swizzled rows
  __shared__ u16 Vts[2][64 * 64];   // V^T tiles [d][kk], XOR-swizzled rows
  __shared__ u16 Ps[64 * 64];       // P tile [q][kk], per-wave rows
  const int tid = threadIdx.x;
  const int bid = blockIdx.x;       // XCD decode: xcd=bid&7 owns 4 (h,b) pairs
  const int t = bid >> 3;
  const int hb = (bid & 7) * 4 + (t >> 5);
  const int qb = t & 31;
  const int h = hb & 15, b = hb >> 4;
  const int wid = tid >> 6, lane = tid & 63;
  const int lo = lane & 15, hi = lane >> 4;
  const int rs = tid >> 3, us = tid & 7;
  const int hoff = h * 64;
  const size_t rowQ0 = (size_t)b * 2048 + (size_t)qb * 64;
  const float QSCALE = 0.125f * 1.4426950408889634f;

  // Q fragments (B-operand): lane holds Q[q = wid*16+lo][d = ks*32 + hi*8 .. +8]
  bf16x8 qf[2];
  #pragma unroll
  for (int ks = 0; ks < 2; ++ks) {
    size_t r = rowQ0 + wid * 16 + lo;
    U16B in; in.i4 = *(const int4*)&Q[r * 1024 + hoff + ks * 32 + hi * 8];
    U16B o;
    #pragma unroll
    for (int j = 0; j < 8; ++j) o.u[j] = f2b(b2f(in.u[j]) * QSCALE);
    qf[ks] = o.b8;
  }

  f32x4 oacc[4];
  const f32x4 z4 = {0.f, 0.f, 0.f, 0.f};
  #pragma unroll
  for (int df = 0; df < 4; ++df) oacc[df] = z4;
  float m_r = -1e30f, l_r = 0.f;   // row stats for q=wid*16+lo (replicated over hi)

  // prologue: stage tile 0 into buffer 0
  #pragma unroll
  for (int c = 0; c < 2; ++c) {
    int r = c * 32 + rs;
    int swu = (us ^ (r & 7)) * 8;
    GLOAD_LDS16(&Kp[((size_t)b * 2048 + r) * 1024 + hoff + swu], &Ks[0][r * 64 + us * 8]);
    GLOAD_LDS16(&VpT[(size_t)(hoff + r) * 4096 + b * 2048 + swu], &Vts[0][r * 64 + us * 8]);
  }

  for (int kb = 0; kb < 32; ++kb) {
    const int cur = kb & 1;
    __syncthreads();   // vmcnt drained: buf[cur] ready; buf[cur^1] readers done
    if (kb < 31) {
      const int kv0 = (kb + 1) * 64;
      #pragma unroll
      for (int c = 0; c < 2; ++c) {
        int r = c * 32 + rs;
        int swu = (us ^ (r & 7)) * 8;
        GLOAD_LDS16(&Kp[((size_t)b * 2048 + kv0 + r) * 1024 + hoff + swu],
                    &Ks[cur ^ 1][r * 64 + us * 8]);
        GLOAD_LDS16(&VpT[(size_t)(hoff + r) * 4096 + b * 2048 + kv0 + swu],
                    &Vts[cur ^ 1][r * 64 + us * 8]);
      }
    }

    // S^T = K Q^T : frag nf covers kk = nf*16 + hi*4 + e, q = wid*16+lo
    f32x4 sfr[4];
    #pragma unroll
    for (int nf = 0; nf < 4; ++nf) sfr[nf] = z4;
    #pragma unroll
    for (int ks = 0; ks < 2; ++ks) {
      #pragma unroll
      for (int nf = 0; nf < 4; ++nf) {
        int kk = nf * 16 + lo;
        bf16x8 kf = *(const bf16x8*)&Ks[cur][kk * 64 + (((ks * 4 + hi) ^ (kk & 7)) << 3)];
        sfr[nf] = __builtin_amdgcn_mfma_f32_16x16x32_bf16(kf, qf[ks], sfr[nf], 0, 0, 0);
      }
    }

    // online softmax with defer-max (16 scores/lane; max3-friendly tree)
    float pm = fmaxf(sfr[0][0], sfr[0][1]);
    pm = fmaxf(fmaxf(pm, sfr[0][2]), sfr[0][3]);
    pm = fmaxf(fmaxf(pm, sfr[1][0]), sfr[1][1]);
    pm = fmaxf(fmaxf(pm, sfr[1][2]), sfr[1][3]);
    pm = fmaxf(fmaxf(pm, sfr[2][0]), sfr[2][1]);
    pm = fmaxf(fmaxf(pm, sfr[2][2]), sfr[2][3]);
    pm = fmaxf(fmaxf(pm, sfr[3][0]), sfr[3][1]);
    pm = fmaxf(fmaxf(pm, sfr[3][2]), sfr[3][3]);
    pm = fmaxf(pm, __shfl_xor(pm, 16));
    pm = fmaxf(pm, __shfl_xor(pm, 32));
    if (!__all(pm <= m_r + 8.0f)) {   // rescale only on real max growth
      float mn = fmaxf(m_r, pm);
      float cc = __builtin_amdgcn_exp2f(m_r - mn);
      m_r = mn;
      l_r *= cc;
      float cce[4];
      #pragma unroll
      for (int e = 0; e < 4; ++e) cce[e] = __shfl(cc, hi * 4 + e);
      #pragma unroll
      for (int df = 0; df < 4; ++df)
        #pragma unroll
        for (int e = 0; e < 4; ++e) oacc[df][e] *= cce[e];
    }
    float ps = 0.f;
    #pragma unroll
    for (int nf = 0; nf < 4; ++nf) {
      PK4 pk;
      #pragma unroll
      for (int e = 0; e < 4; ++e) {
        float p = __builtin_amdgcn_exp2f(sfr[nf][e] - m_r);
        ps += p;
        pk.b[e] = (__bf16)p;     // native cast -> packed cvt
      }
      *(uint2*)&Ps[(wid * 16 + lo) * 64 + ((nf * 16 + hi * 4) ^ ((lo & 7) << 3))] = pk.d2;
    }
    ps += __shfl_xor(ps, 16);
    ps += __shfl_xor(ps, 32);
    l_r += ps;

    // O += P V   (Ps rows are per-wave exclusive: no block barrier)
    #pragma unroll
    for (int ksp = 0; ksp < 2; ++ksp) {
      bf16x8 pa = *(const bf16x8*)&Ps[(wid * 16 + lo) * 64 + ((((ksp * 4 + hi) ^ (lo & 7))) << 3)];
      bf16x8 vb[4];
      #pragma unroll
      for (int df = 0; df < 4; ++df) {
        int d = df * 16 + lo;
        vb[df] = *(const bf16x8*)&Vts[cur][d * 64 + (((ksp * 4 + hi) ^ (d & 7)) << 3)];
      }
      #pragma unroll
      for (int df = 0; df < 4; ++df)
        oacc[df] = __builtin_amdgcn_mfma_f32_16x16x32_bf16(pa, vb[df], oacc[df], 0, 0, 0);
    }
  }

  // epilogue: normalize (stats at q=wid*16+lo; O rows q=hi*4+e -> shfl gather)
  float inv = __builtin_amdgcn_rcpf(l_r);
  float inve[4];
  #pragma unroll
  for (int e = 0; e < 4; ++e) inve[e] = __shfl(inv, hi * 4 + e);
  #pragma unroll
  for (int df = 0; df < 4; ++df)
    #pragma unroll
    for (int e = 0; e < 4; ++e) {
      size_t row = rowQ0 + wid * 16 + hi * 4 + e;
      O[row * 1024 + hoff + df * 16 + lo] = f2b(oacc[df][e] * inve[e]);
    }
}

// ---------------- launch ----------------
extern "C" void kernel_launch(void* const* d_in, const int* in_sizes, int n_in,
                              void* d_out, int out_size, void* d_ws, size_t ws_size,
                              hipStream_t stream) {
  (void)in_sizes; (void)n_in; (void)out_size;
  const size_t MB = 1024 * 1024;
  if (ws_size < 40 * MB) return;
  char* ws = (char*)d_ws;
  u16* Wqt = (u16*)(ws + 0 * MB);
  u16* Wkt = (u16*)(ws + 2 * MB);
  u16* Wvt = (u16*)(ws + 4 * MB);
  u16* Wot = (u16*)(ws + 6 * MB);
  u16* Vb  = (u16*)(ws + 8 * MB);    // bf16 value-input; later reused as Op
  u16* Qp  = (u16*)(ws + 16 * MB);
  u16* Kp  = (u16*)(ws + 24 * MB);
  u16* VpT = (u16*)(ws + 32 * MB);   // V^T [1024][4096]
  u16* Op  = (u16*)(ws + 8 * MB);    // reuse Vb space (dead after QKV GEMM)
  // bf16 query/key inputs parked in d_out (16MB; overwritten by final GEMM)
  u16* Qb = (u16*)d_out;
  u16* Kb = (u16*)d_out + (size_t)4 * MB;   // element offset: 8MB bytes

  ConvA ca;
  ca.src[0] = (const float*)d_in[0]; ca.dst[0] = Qb;
  ca.src[1] = (const float*)d_in[1]; ca.dst[1] = Kb;
  ca.src[2] = (const float*)d_in[2]; ca.dst[2] = Vb;
  hipLaunchKernelGGL(convA, dim3(2048, 1, 3), dim3(256), 0, stream, ca);

  TransA ta;
  ta.W[0] = (const float*)d_in[3]; ta.Wt[0] = Wqt;
  ta.W[1] = (const float*)d_in[5]; ta.Wt[1] = Wkt;
  ta.W[2] = (const float*)d_in[7]; ta.Wt[2] = Wvt;
  ta.W[3] = (const float*)d_in[9]; ta.Wt[3] = Wot;
  hipLaunchKernelGGL(transW, dim3(16, 16, 4), dim3(256), 0, stream, ta);

  GemmB gp;
  gp.A[0] = Qb; gp.Bt[0] = Wqt; gp.bias[0] = (const float*)d_in[4]; gp.C[0] = Qp;  gp.mode[0] = 0;
  gp.A[1] = Kb; gp.Bt[1] = Wkt; gp.bias[1] = (const float*)d_in[6]; gp.C[1] = Kp;  gp.mode[1] = 0;
  gp.A[2] = Vb; gp.Bt[2] = Wvt; gp.bias[2] = (const float*)d_in[8]; gp.C[2] = VpT; gp.mode[2] = 2;
  gp.cpx = 96;
  hipLaunchKernelGGL(gemm_bt, dim3(768), dim3(256), 0, stream, gp);

  hipLaunchKernelGGL(attn_fwd, dim3(1024), dim3(256), 0, stream, Qp, Kp, VpT, Op);

  GemmB gf;
  gf.A[0] = Op; gf.Bt[0] = Wot; gf.bias[0] = (const float*)d_in[10]; gf.C[0] = (void*)d_out; gf.mode[0] = 1;
  gf.A[1] = nullptr; gf.A[2] = nullptr; gf.Bt[1] = nullptr; gf.Bt[2] = nullptr;
  gf.bias[1] = nullptr; gf.bias[2] = nullptr; gf.C[1] = nullptr; gf.C[2] = nullptr;
  gf.mode[1] = 0; gf.mode[2] = 0;
  gf.cpx = 32;
  hipLaunchKernelGGL(gemm_bt, dim3(256), dim3(256), 0, stream, gf);
}

// Round 15
// 146.100 us; speedup vs baseline: 1.4815x; 1.0529x over previous
//
#include <hip/hip_runtime.h>

typedef unsigned short u16;
typedef unsigned int   u32;
typedef __bf16 bf16x8 __attribute__((ext_vector_type(8)));
typedef float  f32x4  __attribute__((ext_vector_type(4)));

union U16B { int4 i4; bf16x8 b8; u16 u[8]; };
union U16Q { uint2 d2; u16 u[4]; };
union PK4  { uint2 d2; __bf16 b[4]; };

static __device__ __forceinline__ u16 f2b(float f) {
  u32 x = __float_as_uint(f);
  x += 0x7FFFu + ((x >> 16) & 1u);   // RNE (inputs finite)
  return (u16)(x >> 16);
}
static __device__ __forceinline__ float b2f(u16 s) {
  return __uint_as_float(((u32)s) << 16);
}

// async global->LDS: dest must be linear (wave-uniform base + lane*16)
#define GLOAD_LDS16(g, l) \
  __builtin_amdgcn_global_load_lds((const __attribute__((address_space(1))) u32*)(g), \
                                   (__attribute__((address_space(3))) u32*)(l), 16, 0, 0)

// ---------------- fp32 -> bf16 convert (inputs, once) ----------------
struct ConvA { const float* src[3]; u16* dst[3]; };

__global__ __launch_bounds__(256) void convA(ConvA a) {
  const float* s = a.src[blockIdx.z];
  u16*         d = a.dst[blockIdx.z];
  const size_t i = ((size_t)blockIdx.x * 256 + threadIdx.x) * 8;
  float4 f0 = *(const float4*)(s + i);
  float4 f1 = *(const float4*)(s + i + 4);
  U16B t;
  t.u[0] = f2b(f0.x); t.u[1] = f2b(f0.y); t.u[2] = f2b(f0.z); t.u[3] = f2b(f0.w);
  t.u[4] = f2b(f1.x); t.u[5] = f2b(f1.y); t.u[6] = f2b(f1.z); t.u[7] = f2b(f1.w);
  *(int4*)(d + i) = t.i4;
}

// ---------------- weight transpose + fp32->bf16 convert ----------------
struct TransA { const float* W[4]; u16* Wt[4]; };

__global__ __launch_bounds__(256) void transW(TransA a) {
  const float* W  = a.W[blockIdx.z];
  u16*         Wt = a.Wt[blockIdx.z];
  __shared__ float t[64][65];
  const int bx = blockIdx.x * 64, by = blockIdx.y * 64;
  const int tx = threadIdx.x & 63, ty = threadIdx.x >> 6;
  #pragma unroll
  for (int j = 0; j < 16; ++j) {
    int row = j * 4 + ty;
    t[row][tx] = W[(size_t)(by + row) * 1024 + bx + tx];
  }
  __syncthreads();
  #pragma unroll
  for (int j = 0; j < 16; ++j) {
    int row = j * 4 + ty;           // Wt[n][k] = W[k][n]
    Wt[(size_t)(bx + row) * 1024 + by + tx] = f2b(t[tx][row]);
  }
}

// ---------------- GEMM: C = A[M][K](bf16) * Bt[N][K]^T + bias ----------------
// BM x 128 tile, BK=64, 4 waves (each (BM/2)x64), m97 2-barrier structure,
// global_load_lds staging (linear dest, pre-swizzled source; rule #21).
// BM=128 for QKV (3 blocks/CU); BM=64 for the final GEMM (512 blocks = 2/CU;
// at BM=128 it was 256 blocks = 1 block/CU -> barrier drains fully exposed).
// mode: 0=bf16 row-major, 1=f32 row-major, 2=bf16 transposed C^T[N][4096].
struct GemmB { const u16* A[3]; const u16* Bt[3]; const float* bias[3]; void* C[3]; int mode[3]; int cpx; int zshift; };

template<int BM>
__global__ __launch_bounds__(256) void gemm_bt(GemmB g) {
  constexpr int K = 1024, N = 1024;
  constexpr int MF = BM / 32;           // 16-row A-fragments per wave
  __shared__ u16 As[BM * 64];
  __shared__ u16 Bs[128 * 64];
  const int bid = blockIdx.x;
  const int lg = (bid & 7) * g.cpx + (bid >> 3);
  const int z = lg >> g.zshift;
  const int rem = lg & ((1 << g.zshift) - 1);
  const int row0 = (rem >> 3) * BM, col0 = (rem & 7) * 128;
  const u16*   Ap   = g.A[z];
  const u16*   Bt   = g.Bt[z];
  const float* bias = g.bias[z];
  const int mode = g.mode[z];
  const int tid = threadIdx.x;
  const int wid = tid >> 6, lane = tid & 63;
  const int wr = wid >> 1, wc = wid & 1;
  const int lo = lane & 15, hi = lane >> 4;
  const int rs = tid >> 3, us = tid & 7;
  const int sw = (us ^ (rs & 7)) * 8;   // pre-swizzled source column unit

  f32x4 acc[MF][4];
  const f32x4 z4 = {0.f, 0.f, 0.f, 0.f};
  #pragma unroll
  for (int i = 0; i < MF; ++i)
    #pragma unroll
    for (int j = 0; j < 4; ++j) acc[i][j] = z4;

  for (int kt = 0; kt < K / 64; ++kt) {
    __syncthreads();
    #pragma unroll
    for (int c = 0; c < MF; ++c) {
      int r = c * 32 + rs;
      GLOAD_LDS16(Ap + (size_t)(row0 + r) * K + kt * 64 + sw, &As[r * 64 + us * 8]);
    }
    #pragma unroll
    for (int c = 0; c < 4; ++c) {
      int r = c * 32 + rs;
      GLOAD_LDS16(Bt + (size_t)(col0 + r) * K + kt * 64 + sw, &Bs[r * 64 + us * 8]);
    }
    __syncthreads();   // compiler drains vmcnt before s_barrier
    #pragma unroll
    for (int ks = 0; ks < 2; ++ks) {
      bf16x8 af[MF], bfr[4];
      #pragma unroll
      for (int mf = 0; mf < MF; ++mf) {
        int r = wr * (BM / 2) + mf * 16 + lo;
        af[mf] = *(const bf16x8*)&As[r * 64 + (((ks * 4 + hi) ^ (r & 7)) << 3)];
      }
      #pragma unroll
      for (int nf = 0; nf < 4; ++nf) {
        int r = wc * 64 + nf * 16 + lo;
        bfr[nf] = *(const bf16x8*)&Bs[r * 64 + (((ks * 4 + hi) ^ (r & 7)) << 3)];
      }
      #pragma unroll
      for (int mf = 0; mf < MF; ++mf)
        #pragma unroll
        for (int nf = 0; nf < 4; ++nf)
          acc[mf][nf] = __builtin_amdgcn_mfma_f32_16x16x32_bf16(af[mf], bfr[nf], acc[mf][nf], 0, 0, 0);
    }
  }

  #pragma unroll
  for (int nf = 0; nf < 4; ++nf) {
    int col = col0 + wc * 64 + nf * 16 + lo;
    float bv = bias[col];
    #pragma unroll
    for (int mf = 0; mf < MF; ++mf) {
      int rb = row0 + wr * (BM / 2) + mf * 16 + hi * 4;   // C/D: row=(l>>4)*4+e, col=l&15
      if (mode == 2) {
        U16Q q4;
        #pragma unroll
        for (int e = 0; e < 4; ++e) q4.u[e] = f2b(acc[mf][nf][e] + bv);
        *(uint2*)&((u16*)g.C[z])[(size_t)col * 4096 + rb] = q4.d2;   // C^T[N][4096]
      } else {
        #pragma unroll
        for (int e = 0; e < 4; ++e) {
          float v = acc[mf][nf][e] + bv;
          if (mode == 1) ((float*)g.C[z])[(size_t)(rb + e) * N + col] = v;
          else           ((u16*)g.C[z])[(size_t)(rb + e) * N + col] = f2b(v);
        }
      }
    }
  }
}

// ---------------- flash attention ----------------
// FROZEN R14 kernel (validated: 72.9us, VGPR=56, WRITE=8MB). dbuf K/V via
// global_load_lds, ONE barrier/iter, defer-max THR=8, PK4 pack, max3 tree.
__global__ __launch_bounds__(256) void attn_fwd(const u16* __restrict__ Q,
                                                const u16* __restrict__ Kp,
                                                const u16* __restrict__ VpT,
                                                u16* __restrict__ O) {
  __shared__ u16 Ks[2][64 * 64];    // K tiles [kk][d], XOR-swizzled rows
  __shared__ u16 Vts[2][64 * 64];   // V^T tiles [d][kk], XOR-swizzled rows
  __shared__ u16 Ps[64 * 64];       // P tile [q][kk], per-wave rows
  const int tid = threadIdx.x;
  const int bid = blockIdx.x;       // XCD decode: xcd=bid&7 owns 4 (h,b) pairs
  const int t = bid >> 3;
  const int hb = (bid & 7) * 4 + (t >> 5);
  const int qb = t & 31;
  const int h = hb & 15, b = hb >> 4;
  const int wid = tid >> 6, lane = tid & 63;
  const int lo = lane & 15, hi = lane >> 4;
  const int rs = tid >> 3, us = tid & 7;
  const int hoff = h * 64;
  const size_t rowQ0 = (size_t)b * 2048 + (size_t)qb * 64;
  const float QSCALE = 0.125f * 1.4426950408889634f;

  // Q fragments (B-operand): lane holds Q[q = wid*16+lo][d = ks*32 + hi*8 .. +8]
  bf16x8 qf[2];
  #pragma unroll
  for (int ks = 0; ks < 2; ++ks) {
    size_t r = rowQ0 + wid * 16 + lo;
    U16B in; in.i4 = *(const int4*)&Q[r * 1024 + hoff + ks * 32 + hi * 8];
    U16B o;
    #pragma unroll
    for (int j = 0; j < 8; ++j) o.u[j] = f2b(b2f(in.u[j]) * QSCALE);
    qf[ks] = o.b8;
  }

  f32x4 oacc[4];
  const f32x4 z4 = {0.f, 0.f, 0.f, 0.f};
  #pragma unroll
  for (int df = 0; df < 4; ++df) oacc[df] = z4;
  float m_r = -1e30f, l_r = 0.f;   // row stats for q=wid*16+lo (replicated over hi)

  // prologue: stage tile 0 into buffer 0
  #pragma unroll
  for (int c = 0; c < 2; ++c) {
    int r = c * 32 + rs;
    int swu = (us ^ (r & 7)) * 8;
    GLOAD_LDS16(&Kp[((size_t)b * 2048 + r) * 1024 + hoff + swu], &Ks[0][r * 64 + us * 8]);
    GLOAD_LDS16(&VpT[(size_t)(hoff + r) * 4096 + b * 2048 + swu], &Vts[0][r * 64 + us * 8]);
  }

  for (int kb = 0; kb < 32; ++kb) {
    const int cur = kb & 1;
    __syncthreads();   // vmcnt drained: buf[cur] ready; buf[cur^1] readers done
    if (kb < 31) {
      const int kv0 = (kb + 1) * 64;
      #pragma unroll
      for (int c = 0; c < 2; ++c) {
        int r = c * 32 + rs;
        int swu = (us ^ (r & 7)) * 8;
        GLOAD_LDS16(&Kp[((size_t)b * 2048 + kv0 + r) * 1024 + hoff + swu],
                    &Ks[cur ^ 1][r * 64 + us * 8]);
        GLOAD_LDS16(&VpT[(size_t)(hoff + r) * 4096 + b * 2048 + kv0 + swu],
                    &Vts[cur ^ 1][r * 64 + us * 8]);
      }
    }

    // S^T = K Q^T : frag nf covers kk = nf*16 + hi*4 + e, q = wid*16+lo
    f32x4 sfr[4];
    #pragma unroll
    for (int nf = 0; nf < 4; ++nf) sfr[nf] = z4;
    #pragma unroll
    for (int ks = 0; ks < 2; ++ks) {
      #pragma unroll
      for (int nf = 0; nf < 4; ++nf) {
        int kk = nf * 16 + lo;
        bf16x8 kf = *(const bf16x8*)&Ks[cur][kk * 64 + (((ks * 4 + hi) ^ (kk & 7)) << 3)];
        sfr[nf] = __builtin_amdgcn_mfma_f32_16x16x32_bf16(kf, qf[ks], sfr[nf], 0, 0, 0);
      }
    }

    // online softmax with defer-max (16 scores/lane; max3-friendly tree)
    float pm = fmaxf(sfr[0][0], sfr[0][1]);
    pm = fmaxf(fmaxf(pm, sfr[0][2]), sfr[0][3]);
    pm = fmaxf(fmaxf(pm, sfr[1][0]), sfr[1][1]);
    pm = fmaxf(fmaxf(pm, sfr[1][2]), sfr[1][3]);
    pm = fmaxf(fmaxf(pm, sfr[2][0]), sfr[2][1]);
    pm = fmaxf(fmaxf(pm, sfr[2][2]), sfr[2][3]);
    pm = fmaxf(fmaxf(pm, sfr[3][0]), sfr[3][1]);
    pm = fmaxf(fmaxf(pm, sfr[3][2]), sfr[3][3]);
    pm = fmaxf(pm, __shfl_xor(pm, 16));
    pm = fmaxf(pm, __shfl_xor(pm, 32));
    if (!__all(pm <= m_r + 8.0f)) {   // rescale only on real max growth
      float mn = fmaxf(m_r, pm);
      float cc = __builtin_amdgcn_exp2f(m_r - mn);
      m_r = mn;
      l_r *= cc;
      float cce[4];
      #pragma unroll
      for (int e = 0; e < 4; ++e) cce[e] = __shfl(cc, hi * 4 + e);
      #pragma unroll
      for (int df = 0; df < 4; ++df)
        #pragma unroll
        for (int e = 0; e < 4; ++e) oacc[df][e] *= cce[e];
    }
    float ps = 0.f;
    #pragma unroll
    for (int nf = 0; nf < 4; ++nf) {
      PK4 pk;
      #pragma unroll
      for (int e = 0; e < 4; ++e) {
        float p = __builtin_amdgcn_exp2f(sfr[nf][e] - m_r);
        ps += p;
        pk.b[e] = (__bf16)p;     // native cast -> packed cvt
      }
      *(uint2*)&Ps[(wid * 16 + lo) * 64 + ((nf * 16 + hi * 4) ^ ((lo & 7) << 3))] = pk.d2;
    }
    ps += __shfl_xor(ps, 16);
    ps += __shfl_xor(ps, 32);
    l_r += ps;

    // O += P V   (Ps rows are per-wave exclusive: no block barrier)
    #pragma unroll
    for (int ksp = 0; ksp < 2; ++ksp) {
      bf16x8 pa = *(const bf16x8*)&Ps[(wid * 16 + lo) * 64 + ((((ksp * 4 + hi) ^ (lo & 7))) << 3)];
      bf16x8 vb[4];
      #pragma unroll
      for (int df = 0; df < 4; ++df) {
        int d = df * 16 + lo;
        vb[df] = *(const bf16x8*)&Vts[cur][d * 64 + (((ksp * 4 + hi) ^ (d & 7)) << 3)];
      }
      #pragma unroll
      for (int df = 0; df < 4; ++df)
        oacc[df] = __builtin_amdgcn_mfma_f32_16x16x32_bf16(pa, vb[df], oacc[df], 0, 0, 0);
    }
  }

  // epilogue: normalize (stats at q=wid*16+lo; O rows q=hi*4+e -> shfl gather)
  float inv = __builtin_amdgcn_rcpf(l_r);
  float inve[4];
  #pragma unroll
  for (int e = 0; e < 4; ++e) inve[e] = __shfl(inv, hi * 4 + e);
  #pragma unroll
  for (int df = 0; df < 4; ++df)
    #pragma unroll
    for (int e = 0; e < 4; ++e) {
      size_t row = rowQ0 + wid * 16 + hi * 4 + e;
      O[row * 1024 + hoff + df * 16 + lo] = f2b(oacc[df][e] * inve[e]);
    }
}

// ---------------- launch ----------------
extern "C" void kernel_launch(void* const* d_in, const int* in_sizes, int n_in,
                              void* d_out, int out_size, void* d_ws, size_t ws_size,
                              hipStream_t stream) {
  (void)in_sizes; (void)n_in; (void)out_size;
  const size_t MB = 1024 * 1024;
  if (ws_size < 40 * MB) return;
  char* ws = (char*)d_ws;
  u16* Wqt = (u16*)(ws + 0 * MB);
  u16* Wkt = (u16*)(ws + 2 * MB);
  u16* Wvt = (u16*)(ws + 4 * MB);
  u16* Wot = (u16*)(ws + 6 * MB);
  u16* Vb  = (u16*)(ws + 8 * MB);    // bf16 value-input; later reused as Op
  u16* Qp  = (u16*)(ws + 16 * MB);
  u16* Kp  = (u16*)(ws + 24 * MB);
  u16* VpT = (u16*)(ws + 32 * MB);   // V^T [1024][4096]
  u16* Op  = (u16*)(ws + 8 * MB);    // reuse Vb space (dead after QKV GEMM)
  // bf16 query/key inputs parked in d_out (16MB; overwritten by final GEMM)
  u16* Qb = (u16*)d_out;
  u16* Kb = (u16*)d_out + (size_t)4 * MB;   // element offset: 8MB bytes

  ConvA ca;
  ca.src[0] = (const float*)d_in[0]; ca.dst[0] = Qb;
  ca.src[1] = (const float*)d_in[1]; ca.dst[1] = Kb;
  ca.src[2] = (const float*)d_in[2]; ca.dst[2] = Vb;
  hipLaunchKernelGGL(convA, dim3(2048, 1, 3), dim3(256), 0, stream, ca);

  TransA ta;
  ta.W[0] = (const float*)d_in[3]; ta.Wt[0] = Wqt;
  ta.W[1] = (const float*)d_in[5]; ta.Wt[1] = Wkt;
  ta.W[2] = (const float*)d_in[7]; ta.Wt[2] = Wvt;
  ta.W[3] = (const float*)d_in[9]; ta.Wt[3] = Wot;
  hipLaunchKernelGGL(transW, dim3(16, 16, 4), dim3(256), 0, stream, ta);

  GemmB gp;
  gp.A[0] = Qb; gp.Bt[0] = Wqt; gp.bias[0] = (const float*)d_in[4]; gp.C[0] = Qp;  gp.mode[0] = 0;
  gp.A[1] = Kb; gp.Bt[1] = Wkt; gp.bias[1] = (const float*)d_in[6]; gp.C[1] = Kp;  gp.mode[1] = 0;
  gp.A[2] = Vb; gp.Bt[2] = Wvt; gp.bias[2] = (const float*)d_in[8]; gp.C[2] = VpT; gp.mode[2] = 2;
  gp.cpx = 96; gp.zshift = 8;
  hipLaunchKernelGGL((gemm_bt<128>), dim3(768), dim3(256), 0, stream, gp);

  hipLaunchKernelGGL(attn_fwd, dim3(1024), dim3(256), 0, stream, Qp, Kp, VpT, Op);

  GemmB gf;
  gf.A[0] = Op; gf.Bt[0] = Wot; gf.bias[0] = (const float*)d_in[10]; gf.C[0] = (void*)d_out; gf.mode[0] = 1;
  gf.A[1] = nullptr; gf.A[2] = nullptr; gf.Bt[1] = nullptr; gf.Bt[2] = nullptr;
  gf.bias[1] = nullptr; gf.bias[2] = nullptr; gf.C[1] = nullptr; gf.C[2] = nullptr;
  gf.mode[1] = 0; gf.mode[2] = 0;
  gf.cpx = 64; gf.zshift = 9;          // 512 blocks, single z
  hipLaunchKernelGGL((gemm_bt<64>), dim3(512), dim3(256), 0, stream, gf);
}

// Round 17
// 134.981 us; speedup vs baseline: 1.6036x; 1.0824x over previous
//
#include <hip/hip_runtime.h>

typedef unsigned short u16;
typedef unsigned int   u32;
typedef __bf16 bf16x8 __attribute__((ext_vector_type(8)));
typedef float  f32x4  __attribute__((ext_vector_type(4)));

union U16B { int4 i4; bf16x8 b8; u16 u[8]; };
union U16Q { uint2 d2; u16 u[4]; };
union PK4  { uint2 d2; __bf16 b[4]; };

static __device__ __forceinline__ u16 f2b(float f) {
  u32 x = __float_as_uint(f);
  x += 0x7FFFu + ((x >> 16) & 1u);   // RNE (inputs finite)
  return (u16)(x >> 16);
}
static __device__ __forceinline__ float b2f(u16 s) {
  return __uint_as_float(((u32)s) << 16);
}

// async global->LDS: dest must be linear (wave-uniform base + lane*16)
#define GLOAD_LDS16(g, l) \
  __builtin_amdgcn_global_load_lds((const __attribute__((address_space(1))) u32*)(g), \
                                   (__attribute__((address_space(3))) u32*)(l), 16, 0, 0)

// ---------------- prep: input fp32->bf16 convert + weight transpose ----------------
// z = 0..2 : convert query/key/value (2048 x-blocks each)
// z = 3    : transpose+convert all 4 weight matrices (x = w*256 + tile; x>=1024 idle)
struct Prep { const float* src[3]; u16* dst[3]; const float* W[4]; u16* Wt[4]; };

__global__ __launch_bounds__(256) void prep(Prep p) {
  if (blockIdx.z < 3) {
    const float* s = p.src[blockIdx.z];
    u16*         d = p.dst[blockIdx.z];
    const size_t i = ((size_t)blockIdx.x * 256 + threadIdx.x) * 8;
    float4 f0 = *(const float4*)(s + i);
    float4 f1 = *(const float4*)(s + i + 4);
    U16B t;
    t.u[0] = f2b(f0.x); t.u[1] = f2b(f0.y); t.u[2] = f2b(f0.z); t.u[3] = f2b(f0.w);
    t.u[4] = f2b(f1.x); t.u[5] = f2b(f1.y); t.u[6] = f2b(f1.z); t.u[7] = f2b(f1.w);
    *(int4*)(d + i) = t.i4;
  } else {
    if (blockIdx.x >= 1024) return;
    const int w = blockIdx.x >> 8, tile = blockIdx.x & 255;
    const float* W  = p.W[w];
    u16*         Wt = p.Wt[w];
    __shared__ float t[64][65];
    const int bx = (tile & 15) * 64, by = (tile >> 4) * 64;
    const int tx = threadIdx.x & 63, ty = threadIdx.x >> 6;
    #pragma unroll
    for (int j = 0; j < 16; ++j) {
      int row = j * 4 + ty;
      t[row][tx] = W[(size_t)(by + row) * 1024 + bx + tx];
    }
    __syncthreads();
    #pragma unroll
    for (int j = 0; j < 16; ++j) {
      int row = j * 4 + ty;           // Wt[n][k] = W[k][n]
      Wt[(size_t)(bx + row) * 1024 + by + tx] = f2b(t[tx][row]);
    }
  }
}

// ---------------- GEMM: C = A[M][K](bf16) * Bt[N][K]^T + bias ----------------
// BM x 128 tile, BK=64, 4 waves (each (BM/2)x64), m97 2-barrier structure,
// global_load_lds staging (linear dest, pre-swizzled source; rule #21).
// BM=64 for BOTH QKV (1536 blocks = 6/CU) and final (512 blocks = 2/CU):
// at K=1024 the 2-barrier K-loop is drain-exposed; co-resident blocks are the
// only latency hiding, so occupancy wins (validated: final GEMM -7.7us @ R15).
// mode: 0=bf16 row-major, 1=f32 row-major, 2=bf16 transposed C^T[N][4096].
struct GemmB { const u16* A[3]; const u16* Bt[3]; const float* bias[3]; void* C[3]; int mode[3]; int cpx; int zshift; };

template<int BM>
__global__ __launch_bounds__(256) void gemm_bt(GemmB g) {
  constexpr int K = 1024, N = 1024;
  constexpr int MF = BM / 32;           // 16-row A-fragments per wave
  __shared__ u16 As[BM * 64];
  __shared__ u16 Bs[128 * 64];
  const int bid = blockIdx.x;
  const int lg = (bid & 7) * g.cpx + (bid >> 3);
  const int z = lg >> g.zshift;
  const int rem = lg & ((1 << g.zshift) - 1);
  const int row0 = (rem >> 3) * BM, col0 = (rem & 7) * 128;
  const u16*   Ap   = g.A[z];
  const u16*   Bt   = g.Bt[z];
  const float* bias = g.bias[z];
  const int mode = g.mode[z];
  const int tid = threadIdx.x;
  const int wid = tid >> 6, lane = tid & 63;
  const int wr = wid >> 1, wc = wid & 1;
  const int lo = lane & 15, hi = lane >> 4;
  const int rs = tid >> 3, us = tid & 7;
  const int sw = (us ^ (rs & 7)) * 8;   // pre-swizzled source column unit

  f32x4 acc[MF][4];
  const f32x4 z4 = {0.f, 0.f, 0.f, 0.f};
  #pragma unroll
  for (int i = 0; i < MF; ++i)
    #pragma unroll
    for (int j = 0; j < 4; ++j) acc[i][j] = z4;

  for (int kt = 0; kt < K / 64; ++kt) {
    __syncthreads();
    #pragma unroll
    for (int c = 0; c < MF; ++c) {
      int r = c * 32 + rs;
      GLOAD_LDS16(Ap + (size_t)(row0 + r) * K + kt * 64 + sw, &As[r * 64 + us * 8]);
    }
    #pragma unroll
    for (int c = 0; c < 4; ++c) {
      int r = c * 32 + rs;
      GLOAD_LDS16(Bt + (size_t)(col0 + r) * K + kt * 64 + sw, &Bs[r * 64 + us * 8]);
    }
    __syncthreads();   // compiler drains vmcnt before s_barrier
    #pragma unroll
    for (int ks = 0; ks < 2; ++ks) {
      bf16x8 af[MF], bfr[4];
      #pragma unroll
      for (int mf = 0; mf < MF; ++mf) {
        int r = wr * (BM / 2) + mf * 16 + lo;
        af[mf] = *(const bf16x8*)&As[r * 64 + (((ks * 4 + hi) ^ (r & 7)) << 3)];
      }
      #pragma unroll
      for (int nf = 0; nf < 4; ++nf) {
        int r = wc * 64 + nf * 16 + lo;
        bfr[nf] = *(const bf16x8*)&Bs[r * 64 + (((ks * 4 + hi) ^ (r & 7)) << 3)];
      }
      #pragma unroll
      for (int mf = 0; mf < MF; ++mf)
        #pragma unroll
        for (int nf = 0; nf < 4; ++nf)
          acc[mf][nf] = __builtin_amdgcn_mfma_f32_16x16x32_bf16(af[mf], bfr[nf], acc[mf][nf], 0, 0, 0);
    }
  }

  #pragma unroll
  for (int nf = 0; nf < 4; ++nf) {
    int col = col0 + wc * 64 + nf * 16 + lo;
    float bv = bias[col];
    #pragma unroll
    for (int mf = 0; mf < MF; ++mf) {
      int rb = row0 + wr * (BM / 2) + mf * 16 + hi * 4;   // C/D: row=(l>>4)*4+e, col=l&15
      if (mode == 2) {
        U16Q q4;
        #pragma unroll
        for (int e = 0; e < 4; ++e) q4.u[e] = f2b(acc[mf][nf][e] + bv);
        *(uint2*)&((u16*)g.C[z])[(size_t)col * 4096 + rb] = q4.d2;   // C^T[N][4096]
      } else {
        #pragma unroll
        for (int e = 0; e < 4; ++e) {
          float v = acc[mf][nf][e] + bv;
          if (mode == 1) ((float*)g.C[z])[(size_t)(rb + e) * N + col] = v;
          else           ((u16*)g.C[z])[(size_t)(rb + e) * N + col] = f2b(v);
        }
      }
    }
  }
}

// ---------------- flash attention ----------------
// FROZEN R14 kernel (validated: 72.9us, VGPR=56, WRITE=8MB). dbuf K/V via
// global_load_lds, ONE barrier/iter, defer-max THR=8, PK4 pack, max3 tree.
__global__ __launch_bounds__(256) void attn_fwd(const u16* __restrict__ Q,
                                                const u16* __restrict__ Kp,
                                                const u16* __restrict__ VpT,
                                                u16* __restrict__ O) {
  __shared__ u16 Ks[2][64 * 64];    // K tiles [kk][d], XOR-swizzled rows
  __shared__ u16 Vts[2][64 * 64];   // V^T tiles [d][kk], XOR-swizzled rows
  __shared__ u16 Ps[64 * 64];       // P tile [q][kk], per-wave rows
  const int tid = threadIdx.x;
  const int bid = blockIdx.x;       // XCD decode: xcd=bid&7 owns 4 (h,b) pairs
  const int t = bid >> 3;
  const int hb = (bid & 7) * 4 + (t >> 5);
  const int qb = t & 31;
  const int h = hb & 15, b = hb >> 4;
  const int wid = tid >> 6, lane = tid & 63;
  const int lo = lane & 15, hi = lane >> 4;
  const int rs = tid >> 3, us = tid & 7;
  const int hoff = h * 64;
  const size_t rowQ0 = (size_t)b * 2048 + (size_t)qb * 64;
  const float QSCALE = 0.125f * 1.4426950408889634f;

  // Q fragments (B-operand): lane holds Q[q = wid*16+lo][d = ks*32 + hi*8 .. +8]
  bf16x8 qf[2];
  #pragma unroll
  for (int ks = 0; ks < 2; ++ks) {
    size_t r = rowQ0 + wid * 16 + lo;
    U16B in; in.i4 = *(const int4*)&Q[r * 1024 + hoff + ks * 32 + hi * 8];
    U16B o;
    #pragma unroll
    for (int j = 0; j < 8; ++j) o.u[j] = f2b(b2f(in.u[j]) * QSCALE);
    qf[ks] = o.b8;
  }

  f32x4 oacc[4];
  const f32x4 z4 = {0.f, 0.f, 0.f, 0.f};
  #pragma unroll
  for (int df = 0; df < 4; ++df) oacc[df] = z4;
  float m_r = -1e30f, l_r = 0.f;   // row stats for q=wid*16+lo (replicated over hi)

  // prologue: stage tile 0 into buffer 0
  #pragma unroll
  for (int c = 0; c < 2; ++c) {
    int r = c * 32 + rs;
    int swu = (us ^ (r & 7)) * 8;
    GLOAD_LDS16(&Kp[((size_t)b * 2048 + r) * 1024 + hoff + swu], &Ks[0][r * 64 + us * 8]);
    GLOAD_LDS16(&VpT[(size_t)(hoff + r) * 4096 + b * 2048 + swu], &Vts[0][r * 64 + us * 8]);
  }

  for (int kb = 0; kb < 32; ++kb) {
    const int cur = kb & 1;
    __syncthreads();   // vmcnt drained: buf[cur] ready; buf[cur^1] readers done
    if (kb < 31) {
      const int kv0 = (kb + 1) * 64;
      #pragma unroll
      for (int c = 0; c < 2; ++c) {
        int r = c * 32 + rs;
        int swu = (us ^ (r & 7)) * 8;
        GLOAD_LDS16(&Kp[((size_t)b * 2048 + kv0 + r) * 1024 + hoff + swu],
                    &Ks[cur ^ 1][r * 64 + us * 8]);
        GLOAD_LDS16(&VpT[(size_t)(hoff + r) * 4096 + b * 2048 + kv0 + swu],
                    &Vts[cur ^ 1][r * 64 + us * 8]);
      }
    }

    // S^T = K Q^T : frag nf covers kk = nf*16 + hi*4 + e, q = wid*16+lo
    f32x4 sfr[4];
    #pragma unroll
    for (int nf = 0; nf < 4; ++nf) sfr[nf] = z4;
    #pragma unroll
    for (int ks = 0; ks < 2; ++ks) {
      #pragma unroll
      for (int nf = 0; nf < 4; ++nf) {
        int kk = nf * 16 + lo;
        bf16x8 kf = *(const bf16x8*)&Ks[cur][kk * 64 + (((ks * 4 + hi) ^ (kk & 7)) << 3)];
        sfr[nf] = __builtin_amdgcn_mfma_f32_16x16x32_bf16(kf, qf[ks], sfr[nf], 0, 0, 0);
      }
    }

    // online softmax with defer-max (16 scores/lane; max3-friendly tree)
    float pm = fmaxf(sfr[0][0], sfr[0][1]);
    pm = fmaxf(fmaxf(pm, sfr[0][2]), sfr[0][3]);
    pm = fmaxf(fmaxf(pm, sfr[1][0]), sfr[1][1]);
    pm = fmaxf(fmaxf(pm, sfr[1][2]), sfr[1][3]);
    pm = fmaxf(fmaxf(pm, sfr[2][0]), sfr[2][1]);
    pm = fmaxf(fmaxf(pm, sfr[2][2]), sfr[2][3]);
    pm = fmaxf(fmaxf(pm, sfr[3][0]), sfr[3][1]);
    pm = fmaxf(fmaxf(pm, sfr[3][2]), sfr[3][3]);
    pm = fmaxf(pm, __shfl_xor(pm, 16));
    pm = fmaxf(pm, __shfl_xor(pm, 32));
    if (!__all(pm <= m_r + 8.0f)) {   // rescale only on real max growth
      float mn = fmaxf(m_r, pm);
      float cc = __builtin_amdgcn_exp2f(m_r - mn);
      m_r = mn;
      l_r *= cc;
      float cce[4];
      #pragma unroll
      for (int e = 0; e < 4; ++e) cce[e] = __shfl(cc, hi * 4 + e);
      #pragma unroll
      for (int df = 0; df < 4; ++df)
        #pragma unroll
        for (int e = 0; e < 4; ++e) oacc[df][e] *= cce[e];
    }
    float ps = 0.f;
    #pragma unroll
    for (int nf = 0; nf < 4; ++nf) {
      PK4 pk;
      #pragma unroll
      for (int e = 0; e < 4; ++e) {
        float p = __builtin_amdgcn_exp2f(sfr[nf][e] - m_r);
        ps += p;
        pk.b[e] = (__bf16)p;     // native cast -> packed cvt
      }
      *(uint2*)&Ps[(wid * 16 + lo) * 64 + ((nf * 16 + hi * 4) ^ ((lo & 7) << 3))] = pk.d2;
    }
    ps += __shfl_xor(ps, 16);
    ps += __shfl_xor(ps, 32);
    l_r += ps;

    // O += P V   (Ps rows are per-wave exclusive: no block barrier)
    #pragma unroll
    for (int ksp = 0; ksp < 2; ++ksp) {
      bf16x8 pa = *(const bf16x8*)&Ps[(wid * 16 + lo) * 64 + ((((ksp * 4 + hi) ^ (lo & 7))) << 3)];
      bf16x8 vb[4];
      #pragma unroll
      for (int df = 0; df < 4; ++df) {
        int d = df * 16 + lo;
        vb[df] = *(const bf16x8*)&Vts[cur][d * 64 + (((ksp * 4 + hi) ^ (d & 7)) << 3)];
      }
      #pragma unroll
      for (int df = 0; df < 4; ++df)
        oacc[df] = __builtin_amdgcn_mfma_f32_16x16x32_bf16(pa, vb[df], oacc[df], 0, 0, 0);
    }
  }

  // epilogue: normalize (stats at q=wid*16+lo; O rows q=hi*4+e -> shfl gather)
  float inv = __builtin_amdgcn_rcpf(l_r);
  float inve[4];
  #pragma unroll
  for (int e = 0; e < 4; ++e) inve[e] = __shfl(inv, hi * 4 + e);
  #pragma unroll
  for (int df = 0; df < 4; ++df)
    #pragma unroll
    for (int e = 0; e < 4; ++e) {
      size_t row = rowQ0 + wid * 16 + hi * 4 + e;
      O[row * 1024 + hoff + df * 16 + lo] = f2b(oacc[df][e] * inve[e]);
    }
}

// ---------------- launch ----------------
extern "C" void kernel_launch(void* const* d_in, const int* in_sizes, int n_in,
                              void* d_out, int out_size, void* d_ws, size_t ws_size,
                              hipStream_t stream) {
  (void)in_sizes; (void)n_in; (void)out_size;
  const size_t MB = 1024 * 1024;
  if (ws_size < 40 * MB) return;
  char* ws = (char*)d_ws;
  u16* Wqt = (u16*)(ws + 0 * MB);
  u16* Wkt = (u16*)(ws + 2 * MB);
  u16* Wvt = (u16*)(ws + 4 * MB);
  u16* Wot = (u16*)(ws + 6 * MB);
  u16* Vb  = (u16*)(ws + 8 * MB);    // bf16 value-input; later reused as Op
  u16* Qp  = (u16*)(ws + 16 * MB);
  u16* Kp  = (u16*)(ws + 24 * MB);
  u16* VpT = (u16*)(ws + 32 * MB);   // V^T [1024][4096]
  u16* Op  = (u16*)(ws + 8 * MB);    // reuse Vb space (dead after QKV GEMM)
  // bf16 query/key inputs parked in d_out (16MB; overwritten by final GEMM)
  u16* Qb = (u16*)d_out;
  u16* Kb = (u16*)d_out + (size_t)4 * MB;   // element offset: 8MB bytes

  Prep pp;
  pp.src[0] = (const float*)d_in[0]; pp.dst[0] = Qb;
  pp.src[1] = (const float*)d_in[1]; pp.dst[1] = Kb;
  pp.src[2] = (const float*)d_in[2]; pp.dst[2] = Vb;
  pp.W[0] = (const float*)d_in[3]; pp.Wt[0] = Wqt;
  pp.W[1] = (const float*)d_in[5]; pp.Wt[1] = Wkt;
  pp.W[2] = (const float*)d_in[7]; pp.Wt[2] = Wvt;
  pp.W[3] = (const float*)d_in[9]; pp.Wt[3] = Wot;
  hipLaunchKernelGGL(prep, dim3(2048, 1, 4), dim3(256), 0, stream, pp);

  GemmB gp;
  gp.A[0] = Qb; gp.Bt[0] = Wqt; gp.bias[0] = (const float*)d_in[4]; gp.C[0] = Qp;  gp.mode[0] = 0;
  gp.A[1] = Kb; gp.Bt[1] = Wkt; gp.bias[1] = (const float*)d_in[6]; gp.C[1] = Kp;  gp.mode[1] = 0;
  gp.A[2] = Vb; gp.Bt[2] = Wvt; gp.bias[2] = (const float*)d_in[8]; gp.C[2] = VpT; gp.mode[2] = 2;
  gp.cpx = 192; gp.zshift = 9;         // BM=64: 512 tiles per z, 1536 blocks = 6/CU
  hipLaunchKernelGGL((gemm_bt<64>), dim3(1536), dim3(256), 0, stream, gp);

  hipLaunchKernelGGL(attn_fwd, dim3(1024), dim3(256), 0, stream, Qp, Kp, VpT, Op);

  GemmB gf;
  gf.A[0] = Op; gf.Bt[0] = Wot; gf.bias[0] = (const float*)d_in[10]; gf.C[0] = (void*)d_out; gf.mode[0] = 1;
  gf.A[1] = nullptr; gf.A[2] = nullptr; gf.Bt[1] = nullptr; gf.Bt[2] = nullptr;
  gf.bias[1] = nullptr; gf.bias[2] = nullptr; gf.C[1] = nullptr; gf.C[2] = nullptr;
  gf.mode[1] = 0; gf.mode[2] = 0;
  gf.cpx = 64; gf.zshift = 9;          // 512 blocks = 2/CU
  hipLaunchKernelGGL((gemm_bt<64>), dim3(512), dim3(256), 0, stream, gf);
}

// Round 18
// 129.775 us; speedup vs baseline: 1.6679x; 1.0401x over previous
//
#include <hip/hip_runtime.h>

typedef unsigned short u16;
typedef unsigned int   u32;
typedef __bf16 bf16x8 __attribute__((ext_vector_type(8)));
typedef float  f32x4  __attribute__((ext_vector_type(4)));

union U16B { int4 i4; bf16x8 b8; u16 u[8]; };
union U16Q { uint2 d2; u16 u[4]; };
union PK4  { uint2 d2; __bf16 b[4]; };

static __device__ __forceinline__ u16 f2b(float f) {
  u32 x = __float_as_uint(f);
  x += 0x7FFFu + ((x >> 16) & 1u);   // RNE (inputs finite)
  return (u16)(x >> 16);
}
static __device__ __forceinline__ float b2f(u16 s) {
  return __uint_as_float(((u32)s) << 16);
}

// async global->LDS: dest must be linear (wave-uniform base + lane*16)
#define GLOAD_LDS16(g, l) \
  __builtin_amdgcn_global_load_lds((const __attribute__((address_space(1))) u32*)(g), \
                                   (__attribute__((address_space(3))) u32*)(l), 16, 0, 0)

// ---------------- prep: input fp32->bf16 convert + weight transpose ----------------
// z = 0..2 : convert query/key/value (2048 x-blocks each)
// z = 3    : transpose+convert all 4 weight matrices (x = w*256 + tile; x>=1024 idle)
struct Prep { const float* src[3]; u16* dst[3]; const float* W[4]; u16* Wt[4]; };

__global__ __launch_bounds__(256) void prep(Prep p) {
  if (blockIdx.z < 3) {
    const float* s = p.src[blockIdx.z];
    u16*         d = p.dst[blockIdx.z];
    const size_t i = ((size_t)blockIdx.x * 256 + threadIdx.x) * 8;
    float4 f0 = *(const float4*)(s + i);
    float4 f1 = *(const float4*)(s + i + 4);
    U16B t;
    t.u[0] = f2b(f0.x); t.u[1] = f2b(f0.y); t.u[2] = f2b(f0.z); t.u[3] = f2b(f0.w);
    t.u[4] = f2b(f1.x); t.u[5] = f2b(f1.y); t.u[6] = f2b(f1.z); t.u[7] = f2b(f1.w);
    *(int4*)(d + i) = t.i4;
  } else {
    if (blockIdx.x >= 1024) return;
    const int w = blockIdx.x >> 8, tile = blockIdx.x & 255;
    const float* W  = p.W[w];
    u16*         Wt = p.Wt[w];
    __shared__ float t[64][65];
    const int bx = (tile & 15) * 64, by = (tile >> 4) * 64;
    const int tx = threadIdx.x & 63, ty = threadIdx.x >> 6;
    #pragma unroll
    for (int j = 0; j < 16; ++j) {
      int row = j * 4 + ty;
      t[row][tx] = W[(size_t)(by + row) * 1024 + bx + tx];
    }
    __syncthreads();
    #pragma unroll
    for (int j = 0; j < 16; ++j) {
      int row = j * 4 + ty;           // Wt[n][k] = W[k][n]
      Wt[(size_t)(bx + row) * 1024 + by + tx] = f2b(t[tx][row]);
    }
  }
}

// ---------------- GEMM: C = A[M][K](bf16) * Bt[N][K]^T + bias ----------------
// BM x 128 tile, BK=64, 4 waves (each (BM/2)x64), m97 2-barrier structure,
// global_load_lds staging (linear dest, pre-swizzled source; rule #21).
// BM=64 for BOTH QKV (1536 blocks = 6/CU) and final (512 blocks = 2/CU):
// co-resident blocks are the 2-barrier K-loop's only latency hiding
// (validated: final GEMM -7.7us @ R15, QKV -11us total @ R17).
// mode: 0=bf16 row-major, 1=f32 row-major, 2=bf16 transposed C^T[N][4096].
struct GemmB { const u16* A[3]; const u16* Bt[3]; const float* bias[3]; void* C[3]; int mode[3]; int cpx; int zshift; };

template<int BM>
__global__ __launch_bounds__(256) void gemm_bt(GemmB g) {
  constexpr int K = 1024, N = 1024;
  constexpr int MF = BM / 32;           // 16-row A-fragments per wave
  __shared__ u16 As[BM * 64];
  __shared__ u16 Bs[128 * 64];
  const int bid = blockIdx.x;
  const int lg = (bid & 7) * g.cpx + (bid >> 3);
  const int z = lg >> g.zshift;
  const int rem = lg & ((1 << g.zshift) - 1);
  const int row0 = (rem >> 3) * BM, col0 = (rem & 7) * 128;
  const u16*   Ap   = g.A[z];
  const u16*   Bt   = g.Bt[z];
  const float* bias = g.bias[z];
  const int mode = g.mode[z];
  const int tid = threadIdx.x;
  const int wid = tid >> 6, lane = tid & 63;
  const int wr = wid >> 1, wc = wid & 1;
  const int lo = lane & 15, hi = lane >> 4;
  const int rs = tid >> 3, us = tid & 7;
  const int sw = (us ^ (rs & 7)) * 8;   // pre-swizzled source column unit

  f32x4 acc[MF][4];
  const f32x4 z4 = {0.f, 0.f, 0.f, 0.f};
  #pragma unroll
  for (int i = 0; i < MF; ++i)
    #pragma unroll
    for (int j = 0; j < 4; ++j) acc[i][j] = z4;

  for (int kt = 0; kt < K / 64; ++kt) {
    __syncthreads();
    #pragma unroll
    for (int c = 0; c < MF; ++c) {
      int r = c * 32 + rs;
      GLOAD_LDS16(Ap + (size_t)(row0 + r) * K + kt * 64 + sw, &As[r * 64 + us * 8]);
    }
    #pragma unroll
    for (int c = 0; c < 4; ++c) {
      int r = c * 32 + rs;
      GLOAD_LDS16(Bt + (size_t)(col0 + r) * K + kt * 64 + sw, &Bs[r * 64 + us * 8]);
    }
    __syncthreads();   // compiler drains vmcnt before s_barrier
    #pragma unroll
    for (int ks = 0; ks < 2; ++ks) {
      bf16x8 af[MF], bfr[4];
      #pragma unroll
      for (int mf = 0; mf < MF; ++mf) {
        int r = wr * (BM / 2) + mf * 16 + lo;
        af[mf] = *(const bf16x8*)&As[r * 64 + (((ks * 4 + hi) ^ (r & 7)) << 3)];
      }
      #pragma unroll
      for (int nf = 0; nf < 4; ++nf) {
        int r = wc * 64 + nf * 16 + lo;
        bfr[nf] = *(const bf16x8*)&Bs[r * 64 + (((ks * 4 + hi) ^ (r & 7)) << 3)];
      }
      #pragma unroll
      for (int mf = 0; mf < MF; ++mf)
        #pragma unroll
        for (int nf = 0; nf < 4; ++nf)
          acc[mf][nf] = __builtin_amdgcn_mfma_f32_16x16x32_bf16(af[mf], bfr[nf], acc[mf][nf], 0, 0, 0);
    }
  }

  #pragma unroll
  for (int nf = 0; nf < 4; ++nf) {
    int col = col0 + wc * 64 + nf * 16 + lo;
    float bv = bias[col];
    #pragma unroll
    for (int mf = 0; mf < MF; ++mf) {
      int rb = row0 + wr * (BM / 2) + mf * 16 + hi * 4;   // C/D: row=(l>>4)*4+e, col=l&15
      if (mode == 2) {
        U16Q q4;
        #pragma unroll
        for (int e = 0; e < 4; ++e) q4.u[e] = f2b(acc[mf][nf][e] + bv);
        *(uint2*)&((u16*)g.C[z])[(size_t)col * 4096 + rb] = q4.d2;   // C^T[N][4096]
      } else {
        #pragma unroll
        for (int e = 0; e < 4; ++e) {
          float v = acc[mf][nf][e] + bv;
          if (mode == 1) ((float*)g.C[z])[(size_t)(rb + e) * N + col] = v;
          else           ((u16*)g.C[z])[(size_t)(rb + e) * N + col] = f2b(v);
        }
      }
    }
  }
}

// ---------------- flash attention ----------------
// R14 base (dbuf gload_lds, one barrier/iter, defer-max THR=8, PK4) + two
// same-family cuts (remove per-iter softmax VALU/DS work; MFMA pipe at 18%):
//  (1) l-via-MFMA: row-sum of P = P @ ones as a 3rd MFMA pair per iter with a
//      constant all-ones B operand. Kills the 16-serial-add ps chain + 2 shfls;
//      lacc lands in C/D layout [q=hi*4+e] so the epilogue gather vanishes too.
//  (2) deferred max-reduce: the defer-max vote needs only per-lane PARTIAL
//      maxes (m_r is row-replicated); the 2 max shfls move into the rare branch.
__global__ __launch_bounds__(256) void attn_fwd(const u16* __restrict__ Q,
                                                const u16* __restrict__ Kp,
                                                const u16* __restrict__ VpT,
                                                u16* __restrict__ O) {
  __shared__ u16 Ks[2][64 * 64];    // K tiles [kk][d], XOR-swizzled rows
  __shared__ u16 Vts[2][64 * 64];   // V^T tiles [d][kk], XOR-swizzled rows
  __shared__ u16 Ps[64 * 64];       // P tile [q][kk], per-wave rows
  const int tid = threadIdx.x;
  const int bid = blockIdx.x;       // XCD decode: xcd=bid&7 owns 4 (h,b) pairs
  const int t = bid >> 3;
  const int hb = (bid & 7) * 4 + (t >> 5);
  const int qb = t & 31;
  const int h = hb & 15, b = hb >> 4;
  const int wid = tid >> 6, lane = tid & 63;
  const int lo = lane & 15, hi = lane >> 4;
  const int rs = tid >> 3, us = tid & 7;
  const int hoff = h * 64;
  const size_t rowQ0 = (size_t)b * 2048 + (size_t)qb * 64;
  const float QSCALE = 0.125f * 1.4426950408889634f;

  // constant all-ones B operand for the l-sum MFMA
  bf16x8 vones;
  {
    U16B t1;
    #pragma unroll
    for (int j = 0; j < 8; ++j) t1.u[j] = 0x3F80u;   // bf16 1.0
    vones = t1.b8;
  }

  // Q fragments (B-operand): lane holds Q[q = wid*16+lo][d = ks*32 + hi*8 .. +8]
  bf16x8 qf[2];
  #pragma unroll
  for (int ks = 0; ks < 2; ++ks) {
    size_t r = rowQ0 + wid * 16 + lo;
    U16B in; in.i4 = *(const int4*)&Q[r * 1024 + hoff + ks * 32 + hi * 8];
    U16B o;
    #pragma unroll
    for (int j = 0; j < 8; ++j) o.u[j] = f2b(b2f(in.u[j]) * QSCALE);
    qf[ks] = o.b8;
  }

  f32x4 oacc[4];
  f32x4 lacc;                       // l in C/D layout: lacc[e] = l[q=hi*4+e]
  const f32x4 z4 = {0.f, 0.f, 0.f, 0.f};
  #pragma unroll
  for (int df = 0; df < 4; ++df) oacc[df] = z4;
  lacc = z4;
  float m_r = -1e30f;               // running max for q=wid*16+lo (replicated over hi)

  // prologue: stage tile 0 into buffer 0
  #pragma unroll
  for (int c = 0; c < 2; ++c) {
    int r = c * 32 + rs;
    int swu = (us ^ (r & 7)) * 8;
    GLOAD_LDS16(&Kp[((size_t)b * 2048 + r) * 1024 + hoff + swu], &Ks[0][r * 64 + us * 8]);
    GLOAD_LDS16(&VpT[(size_t)(hoff + r) * 4096 + b * 2048 + swu], &Vts[0][r * 64 + us * 8]);
  }

  for (int kb = 0; kb < 32; ++kb) {
    const int cur = kb & 1;
    __syncthreads();   // vmcnt drained: buf[cur] ready; buf[cur^1] readers done
    if (kb < 31) {
      const int kv0 = (kb + 1) * 64;
      #pragma unroll
      for (int c = 0; c < 2; ++c) {
        int r = c * 32 + rs;
        int swu = (us ^ (r & 7)) * 8;
        GLOAD_LDS16(&Kp[((size_t)b * 2048 + kv0 + r) * 1024 + hoff + swu],
                    &Ks[cur ^ 1][r * 64 + us * 8]);
        GLOAD_LDS16(&VpT[(size_t)(hoff + r) * 4096 + b * 2048 + kv0 + swu],
                    &Vts[cur ^ 1][r * 64 + us * 8]);
      }
    }

    // S^T = K Q^T : frag nf covers kk = nf*16 + hi*4 + e, q = wid*16+lo
    f32x4 sfr[4];
    #pragma unroll
    for (int nf = 0; nf < 4; ++nf) sfr[nf] = z4;
    #pragma unroll
    for (int ks = 0; ks < 2; ++ks) {
      #pragma unroll
      for (int nf = 0; nf < 4; ++nf) {
        int kk = nf * 16 + lo;
        bf16x8 kf = *(const bf16x8*)&Ks[cur][kk * 64 + (((ks * 4 + hi) ^ (kk & 7)) << 3)];
        sfr[nf] = __builtin_amdgcn_mfma_f32_16x16x32_bf16(kf, qf[ks], sfr[nf], 0, 0, 0);
      }
    }

    // defer-max vote on PER-LANE partial max (no shfl on the fast path):
    // row max > m_r+8  <=>  some lane's partial > m_r+8 (m_r row-replicated)
    float pm = fmaxf(sfr[0][0], sfr[0][1]);
    pm = fmaxf(fmaxf(pm, sfr[0][2]), sfr[0][3]);
    pm = fmaxf(fmaxf(pm, sfr[1][0]), sfr[1][1]);
    pm = fmaxf(fmaxf(pm, sfr[1][2]), sfr[1][3]);
    pm = fmaxf(fmaxf(pm, sfr[2][0]), sfr[2][1]);
    pm = fmaxf(fmaxf(pm, sfr[2][2]), sfr[2][3]);
    pm = fmaxf(fmaxf(pm, sfr[3][0]), sfr[3][1]);
    pm = fmaxf(fmaxf(pm, sfr[3][2]), sfr[3][3]);
    if (!__all(pm <= m_r + 8.0f)) {   // rare: real max growth -> full reduce+rescale
      pm = fmaxf(pm, __shfl_xor(pm, 16));
      pm = fmaxf(pm, __shfl_xor(pm, 32));
      float mn = fmaxf(m_r, pm);
      float cc = __builtin_amdgcn_exp2f(m_r - mn);
      m_r = mn;
      float cce[4];
      #pragma unroll
      for (int e = 0; e < 4; ++e) cce[e] = __shfl(cc, hi * 4 + e);
      #pragma unroll
      for (int df = 0; df < 4; ++df)
        #pragma unroll
        for (int e = 0; e < 4; ++e) oacc[df][e] *= cce[e];
      #pragma unroll
      for (int e = 0; e < 4; ++e) lacc[e] *= cce[e];
    }
    // P pack (no ps accumulation — l comes from the ones-MFMA below)
    #pragma unroll
    for (int nf = 0; nf < 4; ++nf) {
      PK4 pk;
      #pragma unroll
      for (int e = 0; e < 4; ++e)
        pk.b[e] = (__bf16)__builtin_amdgcn_exp2f(sfr[nf][e] - m_r);
      *(uint2*)&Ps[(wid * 16 + lo) * 64 + ((nf * 16 + hi * 4) ^ ((lo & 7) << 3))] = pk.d2;
    }

    // O += P V ; l += P @ ones   (Ps rows per-wave exclusive: no block barrier)
    #pragma unroll
    for (int ksp = 0; ksp < 2; ++ksp) {
      bf16x8 pa = *(const bf16x8*)&Ps[(wid * 16 + lo) * 64 + ((((ksp * 4 + hi) ^ (lo & 7))) << 3)];
      bf16x8 vb[4];
      #pragma unroll
      for (int df = 0; df < 4; ++df) {
        int d = df * 16 + lo;
        vb[df] = *(const bf16x8*)&Vts[cur][d * 64 + (((ksp * 4 + hi) ^ (d & 7)) << 3)];
      }
      #pragma unroll
      for (int df = 0; df < 4; ++df)
        oacc[df] = __builtin_amdgcn_mfma_f32_16x16x32_bf16(pa, vb[df], oacc[df], 0, 0, 0);
      lacc = __builtin_amdgcn_mfma_f32_16x16x32_bf16(pa, vones, lacc, 0, 0, 0);
    }
  }

  // epilogue: lacc[e] = l[q=hi*4+e] is already in output layout -> no gather
  float inve[4];
  #pragma unroll
  for (int e = 0; e < 4; ++e) inve[e] = __builtin_amdgcn_rcpf(lacc[e]);
  #pragma unroll
  for (int df = 0; df < 4; ++df)
    #pragma unroll
    for (int e = 0; e < 4; ++e) {
      size_t row = rowQ0 + wid * 16 + hi * 4 + e;
      O[row * 1024 + hoff + df * 16 + lo] = f2b(oacc[df][e] * inve[e]);
    }
}

// ---------------- launch ----------------
extern "C" void kernel_launch(void* const* d_in, const int* in_sizes, int n_in,
                              void* d_out, int out_size, void* d_ws, size_t ws_size,
                              hipStream_t stream) {
  (void)in_sizes; (void)n_in; (void)out_size;
  const size_t MB = 1024 * 1024;
  if (ws_size < 40 * MB) return;
  char* ws = (char*)d_ws;
  u16* Wqt = (u16*)(ws + 0 * MB);
  u16* Wkt = (u16*)(ws + 2 * MB);
  u16* Wvt = (u16*)(ws + 4 * MB);
  u16* Wot = (u16*)(ws + 6 * MB);
  u16* Vb  = (u16*)(ws + 8 * MB);    // bf16 value-input; later reused as Op
  u16* Qp  = (u16*)(ws + 16 * MB);
  u16* Kp  = (u16*)(ws + 24 * MB);
  u16* VpT = (u16*)(ws + 32 * MB);   // V^T [1024][4096]
  u16* Op  = (u16*)(ws + 8 * MB);    // reuse Vb space (dead after QKV GEMM)
  // bf16 query/key inputs parked in d_out (16MB; overwritten by final GEMM)
  u16* Qb = (u16*)d_out;
  u16* Kb = (u16*)d_out + (size_t)4 * MB;   // element offset: 8MB bytes

  Prep pp;
  pp.src[0] = (const float*)d_in[0]; pp.dst[0] = Qb;
  pp.src[1] = (const float*)d_in[1]; pp.dst[1] = Kb;
  pp.src[2] = (const float*)d_in[2]; pp.dst[2] = Vb;
  pp.W[0] = (const float*)d_in[3]; pp.Wt[0] = Wqt;
  pp.W[1] = (const float*)d_in[5]; pp.Wt[1] = Wkt;
  pp.W[2] = (const float*)d_in[7]; pp.Wt[2] = Wvt;
  pp.W[3] = (const float*)d_in[9]; pp.Wt[3] = Wot;
  hipLaunchKernelGGL(prep, dim3(2048, 1, 4), dim3(256), 0, stream, pp);

  GemmB gp;
  gp.A[0] = Qb; gp.Bt[0] = Wqt; gp.bias[0] = (const float*)d_in[4]; gp.C[0] = Qp;  gp.mode[0] = 0;
  gp.A[1] = Kb; gp.Bt[1] = Wkt; gp.bias[1] = (const float*)d_in[6]; gp.C[1] = Kp;  gp.mode[1] = 0;
  gp.A[2] = Vb; gp.Bt[2] = Wvt; gp.bias[2] = (const float*)d_in[8]; gp.C[2] = VpT; gp.mode[2] = 2;
  gp.cpx = 192; gp.zshift = 9;         // BM=64: 512 tiles per z, 1536 blocks = 6/CU
  hipLaunchKernelGGL((gemm_bt<64>), dim3(1536), dim3(256), 0, stream, gp);

  hipLaunchKernelGGL(attn_fwd, dim3(1024), dim3(256), 0, stream, Qp, Kp, VpT, Op);

  GemmB gf;
  gf.A[0] = Op; gf.Bt[0] = Wot; gf.bias[0] = (const float*)d_in[10]; gf.C[0] = (void*)d_out; gf.mode[0] = 1;
  gf.A[1] = nullptr; gf.A[2] = nullptr; gf.Bt[1] = nullptr; gf.Bt[2] = nullptr;
  gf.bias[1] = nullptr; gf.bias[2] = nullptr; gf.C[1] = nullptr; gf.C[2] = nullptr;
  gf.mode[1] = 0; gf.mode[2] = 0;
  gf.cpx = 64; gf.zshift = 9;          // 512 blocks = 2/CU
  hipLaunchKernelGGL((gemm_bt<64>), dim3(512), dim3(256), 0, stream, gf);
}

// Round 19
// 129.720 us; speedup vs baseline: 1.6686x; 1.0004x over previous
//
#include <hip/hip_runtime.h>

typedef unsigned short u16;
typedef unsigned int   u32;
typedef __bf16 bf16x8 __attribute__((ext_vector_type(8)));
typedef float  f32x4  __attribute__((ext_vector_type(4)));

union U16B { int4 i4; bf16x8 b8; u16 u[8]; };
union U16Q { uint2 d2; u16 u[4]; };
union PK4  { uint2 d2; __bf16 b[4]; };

static __device__ __forceinline__ u16 f2b(float f) {
  u32 x = __float_as_uint(f);
  x += 0x7FFFu + ((x >> 16) & 1u);   // RNE (inputs finite)
  return (u16)(x >> 16);
}
static __device__ __forceinline__ float b2f(u16 s) {
  return __uint_as_float(((u32)s) << 16);
}

// async global->LDS: dest must be linear (wave-uniform base + lane*16)
#define GLOAD_LDS16(g, l) \
  __builtin_amdgcn_global_load_lds((const __attribute__((address_space(1))) u32*)(g), \
                                   (__attribute__((address_space(3))) u32*)(l), 16, 0, 0)

// ---------------- prep: input fp32->bf16 convert + weight transpose ----------------
// z = 0..2 : convert query/key/value (2048 x-blocks each)
// z = 3    : transpose+convert all 4 weight matrices (x = w*256 + tile; x>=1024 idle)
struct Prep { const float* src[3]; u16* dst[3]; const float* W[4]; u16* Wt[4]; };

__global__ __launch_bounds__(256) void prep(Prep p) {
  if (blockIdx.z < 3) {
    const float* s = p.src[blockIdx.z];
    u16*         d = p.dst[blockIdx.z];
    const size_t i = ((size_t)blockIdx.x * 256 + threadIdx.x) * 8;
    float4 f0 = *(const float4*)(s + i);
    float4 f1 = *(const float4*)(s + i + 4);
    U16B t;
    t.u[0] = f2b(f0.x); t.u[1] = f2b(f0.y); t.u[2] = f2b(f0.z); t.u[3] = f2b(f0.w);
    t.u[4] = f2b(f1.x); t.u[5] = f2b(f1.y); t.u[6] = f2b(f1.z); t.u[7] = f2b(f1.w);
    *(int4*)(d + i) = t.i4;
  } else {
    if (blockIdx.x >= 1024) return;
    const int w = blockIdx.x >> 8, tile = blockIdx.x & 255;
    const float* W  = p.W[w];
    u16*         Wt = p.Wt[w];
    __shared__ float t[64][65];
    const int bx = (tile & 15) * 64, by = (tile >> 4) * 64;
    const int tx = threadIdx.x & 63, ty = threadIdx.x >> 6;
    #pragma unroll
    for (int j = 0; j < 16; ++j) {
      int row = j * 4 + ty;
      t[row][tx] = W[(size_t)(by + row) * 1024 + bx + tx];
    }
    __syncthreads();
    #pragma unroll
    for (int j = 0; j < 16; ++j) {
      int row = j * 4 + ty;           // Wt[n][k] = W[k][n]
      Wt[(size_t)(bx + row) * 1024 + by + tx] = f2b(t[tx][row]);
    }
  }
}

// ---------------- GEMM: C = A[M][K](bf16) * Bt[N][K]^T + bias ----------------
// BM x 128 tile, BK=64, 4 waves, m97 2-barrier structure, global_load_lds
// staging (linear dest, pre-swizzled source; rule #21). BM=64 everywhere
// (QKV 1536 blocks = 6/CU, final 512 = 2/CU; occupancy lever validated
// R15/R17). R19: staging addresses strength-reduced to running pointers.
struct GemmB { const u16* A[3]; const u16* Bt[3]; const float* bias[3]; void* C[3]; int mode[3]; int cpx; int zshift; };

template<int BM>
__global__ __launch_bounds__(256) void gemm_bt(GemmB g) {
  constexpr int K = 1024, N = 1024;
  constexpr int MF = BM / 32;           // 16-row A-fragments per wave
  __shared__ u16 As[BM * 64];
  __shared__ u16 Bs[128 * 64];
  const int bid = blockIdx.x;
  const int lg = (bid & 7) * g.cpx + (bid >> 3);
  const int z = lg >> g.zshift;
  const int rem = lg & ((1 << g.zshift) - 1);
  const int row0 = (rem >> 3) * BM, col0 = (rem & 7) * 128;
  const u16*   Ap   = g.A[z];
  const u16*   Bt   = g.Bt[z];
  const float* bias = g.bias[z];
  const int mode = g.mode[z];
  const int tid = threadIdx.x;
  const int wid = tid >> 6, lane = tid & 63;
  const int wr = wid >> 1, wc = wid & 1;
  const int lo = lane & 15, hi = lane >> 4;
  const int rs = tid >> 3, us = tid & 7;
  const int sw = (us ^ (rs & 7)) * 8;   // pre-swizzled source column unit

  // running staging pointers (advance +64/iter; removes per-iter 64b addr math)
  const u16* aG[MF];
  const u16* bG[4];
  #pragma unroll
  for (int c = 0; c < MF; ++c) aG[c] = Ap + (size_t)(row0 + c * 32 + rs) * K + sw;
  #pragma unroll
  for (int c = 0; c < 4; ++c)  bG[c] = Bt + (size_t)(col0 + c * 32 + rs) * K + sw;

  f32x4 acc[MF][4];
  const f32x4 z4 = {0.f, 0.f, 0.f, 0.f};
  #pragma unroll
  for (int i = 0; i < MF; ++i)
    #pragma unroll
    for (int j = 0; j < 4; ++j) acc[i][j] = z4;

  for (int kt = 0; kt < K / 64; ++kt) {
    __syncthreads();
    #pragma unroll
    for (int c = 0; c < MF; ++c) {
      GLOAD_LDS16(aG[c], &As[(c * 32 + rs) * 64 + us * 8]);
      aG[c] += 64;
    }
    #pragma unroll
    for (int c = 0; c < 4; ++c) {
      GLOAD_LDS16(bG[c], &Bs[(c * 32 + rs) * 64 + us * 8]);
      bG[c] += 64;
    }
    __syncthreads();   // compiler drains vmcnt before s_barrier
    #pragma unroll
    for (int ks = 0; ks < 2; ++ks) {
      bf16x8 af[MF], bfr[4];
      #pragma unroll
      for (int mf = 0; mf < MF; ++mf) {
        int r = wr * (BM / 2) + mf * 16 + lo;
        af[mf] = *(const bf16x8*)&As[r * 64 + (((ks * 4 + hi) ^ (r & 7)) << 3)];
      }
      #pragma unroll
      for (int nf = 0; nf < 4; ++nf) {
        int r = wc * 64 + nf * 16 + lo;
        bfr[nf] = *(const bf16x8*)&Bs[r * 64 + (((ks * 4 + hi) ^ (r & 7)) << 3)];
      }
      #pragma unroll
      for (int mf = 0; mf < MF; ++mf)
        #pragma unroll
        for (int nf = 0; nf < 4; ++nf)
          acc[mf][nf] = __builtin_amdgcn_mfma_f32_16x16x32_bf16(af[mf], bfr[nf], acc[mf][nf], 0, 0, 0);
    }
  }

  #pragma unroll
  for (int nf = 0; nf < 4; ++nf) {
    int col = col0 + wc * 64 + nf * 16 + lo;
    float bv = bias[col];
    #pragma unroll
    for (int mf = 0; mf < MF; ++mf) {
      int rb = row0 + wr * (BM / 2) + mf * 16 + hi * 4;   // C/D: row=(l>>4)*4+e, col=l&15
      if (mode == 2) {
        U16Q q4;
        #pragma unroll
        for (int e = 0; e < 4; ++e) q4.u[e] = f2b(acc[mf][nf][e] + bv);
        *(uint2*)&((u16*)g.C[z])[(size_t)col * 4096 + rb] = q4.d2;   // C^T[N][4096]
      } else {
        #pragma unroll
        for (int e = 0; e < 4; ++e) {
          float v = acc[mf][nf][e] + bv;
          if (mode == 1) ((float*)g.C[z])[(size_t)(rb + e) * N + col] = v;
          else           ((u16*)g.C[z])[(size_t)(rb + e) * N + col] = f2b(v);
        }
      }
    }
  }
}

// ---------------- flash attention ----------------
// R18 base (dbuf gload_lds, one barrier/iter, defer-max THR=8, PK4, l-via-MFMA,
// deferred max-reduce). R19: staging addresses strength-reduced to running
// pointers (4 global ptr + precomputed LDS dests, cndmask buffer select) —
// removes ~20 VALU 64b-mad ops per iteration.
__global__ __launch_bounds__(256) void attn_fwd(const u16* __restrict__ Q,
                                                const u16* __restrict__ Kp,
                                                const u16* __restrict__ VpT,
                                                u16* __restrict__ O) {
  __shared__ u16 Ks[2][64 * 64];    // K tiles [kk][d], XOR-swizzled rows
  __shared__ u16 Vts[2][64 * 64];   // V^T tiles [d][kk], XOR-swizzled rows
  __shared__ u16 Ps[64 * 64];       // P tile [q][kk], per-wave rows
  const int tid = threadIdx.x;
  const int bid = blockIdx.x;       // XCD decode: xcd=bid&7 owns 4 (h,b) pairs
  const int t = bid >> 3;
  const int hb = (bid & 7) * 4 + (t >> 5);
  const int qb = t & 31;
  const int h = hb & 15, b = hb >> 4;
  const int wid = tid >> 6, lane = tid & 63;
  const int lo = lane & 15, hi = lane >> 4;
  const int rs = tid >> 3, us = tid & 7;
  const int hoff = h * 64;
  const size_t rowQ0 = (size_t)b * 2048 + (size_t)qb * 64;
  const float QSCALE = 0.125f * 1.4426950408889634f;

  // constant all-ones B operand for the l-sum MFMA
  bf16x8 vones;
  {
    U16B t1;
    #pragma unroll
    for (int j = 0; j < 8; ++j) t1.u[j] = 0x3F80u;   // bf16 1.0
    vones = t1.b8;
  }

  // Q fragments (B-operand): lane holds Q[q = wid*16+lo][d = ks*32 + hi*8 .. +8]
  bf16x8 qf[2];
  #pragma unroll
  for (int ks = 0; ks < 2; ++ks) {
    size_t r = rowQ0 + wid * 16 + lo;
    U16B in; in.i4 = *(const int4*)&Q[r * 1024 + hoff + ks * 32 + hi * 8];
    U16B o;
    #pragma unroll
    for (int j = 0; j < 8; ++j) o.u[j] = f2b(b2f(in.u[j]) * QSCALE);
    qf[ks] = o.b8;
  }

  f32x4 oacc[4];
  f32x4 lacc;                       // l in C/D layout: lacc[e] = l[q=hi*4+e]
  const f32x4 z4 = {0.f, 0.f, 0.f, 0.f};
  #pragma unroll
  for (int df = 0; df < 4; ++df) oacc[df] = z4;
  lacc = z4;
  float m_r = -1e30f;               // running max for q=wid*16+lo (replicated over hi)

  // running staging pointers (swu identical for both row-chunks: (c*32+rs)&7 == rs&7)
  const int swu = (us ^ (rs & 7)) * 8;
  const u16* kGa = Kp + ((size_t)b * 2048 + rs) * 1024 + hoff + swu;           // row rs
  const u16* kGb = kGa + 32 * 1024;                                            // row 32+rs
  const u16* vGa = VpT + (size_t)(hoff + rs) * 4096 + (size_t)b * 2048 + swu;  // row rs
  const u16* vGb = vGa + (size_t)32 * 4096;                                    // row 32+rs
  u16* dK0 = &Ks[0][rs * 64 + us * 8];
  u16* dK1 = &Ks[1][rs * 64 + us * 8];
  u16* dV0 = &Vts[0][rs * 64 + us * 8];
  u16* dV1 = &Vts[1][rs * 64 + us * 8];

  // prologue: stage tile 0 into buffer 0
  GLOAD_LDS16(kGa, dK0); GLOAD_LDS16(kGb, dK0 + 32 * 64);
  GLOAD_LDS16(vGa, dV0); GLOAD_LDS16(vGb, dV0 + 32 * 64);
  kGa += 64 * 1024; kGb += 64 * 1024; vGa += 64; vGb += 64;

  for (int kb = 0; kb < 32; ++kb) {
    const int cur = kb & 1;
    __syncthreads();   // vmcnt drained: buf[cur] ready; buf[cur^1] readers done
    if (kb < 31) {
      u16* dK = cur ? dK0 : dK1;
      u16* dV = cur ? dV0 : dV1;
      GLOAD_LDS16(kGa, dK); GLOAD_LDS16(kGb, dK + 32 * 64);
      GLOAD_LDS16(vGa, dV); GLOAD_LDS16(vGb, dV + 32 * 64);
      kGa += 64 * 1024; kGb += 64 * 1024; vGa += 64; vGb += 64;
    }

    // S^T = K Q^T : frag nf covers kk = nf*16 + hi*4 + e, q = wid*16+lo
    f32x4 sfr[4];
    #pragma unroll
    for (int nf = 0; nf < 4; ++nf) sfr[nf] = z4;
    #pragma unroll
    for (int ks = 0; ks < 2; ++ks) {
      #pragma unroll
      for (int nf = 0; nf < 4; ++nf) {
        int kk = nf * 16 + lo;
        bf16x8 kf = *(const bf16x8*)&Ks[cur][kk * 64 + (((ks * 4 + hi) ^ (kk & 7)) << 3)];
        sfr[nf] = __builtin_amdgcn_mfma_f32_16x16x32_bf16(kf, qf[ks], sfr[nf], 0, 0, 0);
      }
    }

    // defer-max vote on PER-LANE partial max (no shfl on the fast path)
    float pm = fmaxf(sfr[0][0], sfr[0][1]);
    pm = fmaxf(fmaxf(pm, sfr[0][2]), sfr[0][3]);
    pm = fmaxf(fmaxf(pm, sfr[1][0]), sfr[1][1]);
    pm = fmaxf(fmaxf(pm, sfr[1][2]), sfr[1][3]);
    pm = fmaxf(fmaxf(pm, sfr[2][0]), sfr[2][1]);
    pm = fmaxf(fmaxf(pm, sfr[2][2]), sfr[2][3]);
    pm = fmaxf(fmaxf(pm, sfr[3][0]), sfr[3][1]);
    pm = fmaxf(fmaxf(pm, sfr[3][2]), sfr[3][3]);
    if (!__all(pm <= m_r + 8.0f)) {   // rare: real max growth -> full reduce+rescale
      pm = fmaxf(pm, __shfl_xor(pm, 16));
      pm = fmaxf(pm, __shfl_xor(pm, 32));
      float mn = fmaxf(m_r, pm);
      float cc = __builtin_amdgcn_exp2f(m_r - mn);
      m_r = mn;
      float cce[4];
      #pragma unroll
      for (int e = 0; e < 4; ++e) cce[e] = __shfl(cc, hi * 4 + e);
      #pragma unroll
      for (int df = 0; df < 4; ++df)
        #pragma unroll
        for (int e = 0; e < 4; ++e) oacc[df][e] *= cce[e];
      #pragma unroll
      for (int e = 0; e < 4; ++e) lacc[e] *= cce[e];
    }
    // P pack (l comes from the ones-MFMA below)
    #pragma unroll
    for (int nf = 0; nf < 4; ++nf) {
      PK4 pk;
      #pragma unroll
      for (int e = 0; e < 4; ++e)
        pk.b[e] = (__bf16)__builtin_amdgcn_exp2f(sfr[nf][e] - m_r);
      *(uint2*)&Ps[(wid * 16 + lo) * 64 + ((nf * 16 + hi * 4) ^ ((lo & 7) << 3))] = pk.d2;
    }

    // O += P V ; l += P @ ones   (Ps rows per-wave exclusive: no block barrier)
    #pragma unroll
    for (int ksp = 0; ksp < 2; ++ksp) {
      bf16x8 pa = *(const bf16x8*)&Ps[(wid * 16 + lo) * 64 + ((((ksp * 4 + hi) ^ (lo & 7))) << 3)];
      bf16x8 vb[4];
      #pragma unroll
      for (int df = 0; df < 4; ++df) {
        int d = df * 16 + lo;
        vb[df] = *(const bf16x8*)&Vts[cur][d * 64 + (((ksp * 4 + hi) ^ (d & 7)) << 3)];
      }
      #pragma unroll
      for (int df = 0; df < 4; ++df)
        oacc[df] = __builtin_amdgcn_mfma_f32_16x16x32_bf16(pa, vb[df], oacc[df], 0, 0, 0);
      lacc = __builtin_amdgcn_mfma_f32_16x16x32_bf16(pa, vones, lacc, 0, 0, 0);
    }
  }

  // epilogue: lacc[e] = l[q=hi*4+e] already in output layout -> no gather
  float inve[4];
  #pragma unroll
  for (int e = 0; e < 4; ++e) inve[e] = __builtin_amdgcn_rcpf(lacc[e]);
  #pragma unroll
  for (int df = 0; df < 4; ++df)
    #pragma unroll
    for (int e = 0; e < 4; ++e) {
      size_t row = rowQ0 + wid * 16 + hi * 4 + e;
      O[row * 1024 + hoff + df * 16 + lo] = f2b(oacc[df][e] * inve[e]);
    }
}

// ---------------- launch ----------------
extern "C" void kernel_launch(void* const* d_in, const int* in_sizes, int n_in,
                              void* d_out, int out_size, void* d_ws, size_t ws_size,
                              hipStream_t stream) {
  (void)in_sizes; (void)n_in; (void)out_size;
  const size_t MB = 1024 * 1024;
  if (ws_size < 40 * MB) return;
  char* ws = (char*)d_ws;
  u16* Wqt = (u16*)(ws + 0 * MB);
  u16* Wkt = (u16*)(ws + 2 * MB);
  u16* Wvt = (u16*)(ws + 4 * MB);
  u16* Wot = (u16*)(ws + 6 * MB);
  u16* Vb  = (u16*)(ws + 8 * MB);    // bf16 value-input; later reused as Op
  u16* Qp  = (u16*)(ws + 16 * MB);
  u16* Kp  = (u16*)(ws + 24 * MB);
  u16* VpT = (u16*)(ws + 32 * MB);   // V^T [1024][4096]
  u16* Op  = (u16*)(ws + 8 * MB);    // reuse Vb space (dead after QKV GEMM)
  // bf16 query/key inputs parked in d_out (16MB; overwritten by final GEMM)
  u16* Qb = (u16*)d_out;
  u16* Kb = (u16*)d_out + (size_t)4 * MB;   // element offset: 8MB bytes

  Prep pp;
  pp.src[0] = (const float*)d_in[0]; pp.dst[0] = Qb;
  pp.src[1] = (const float*)d_in[1]; pp.dst[1] = Kb;
  pp.src[2] = (const float*)d_in[2]; pp.dst[2] = Vb;
  pp.W[0] = (const float*)d_in[3]; pp.Wt[0] = Wqt;
  pp.W[1] = (const float*)d_in[5]; pp.Wt[1] = Wkt;
  pp.W[2] = (const float*)d_in[7]; pp.Wt[2] = Wvt;
  pp.W[3] = (const float*)d_in[9]; pp.Wt[3] = Wot;
  hipLaunchKernelGGL(prep, dim3(2048, 1, 4), dim3(256), 0, stream, pp);

  GemmB gp;
  gp.A[0] = Qb; gp.Bt[0] = Wqt; gp.bias[0] = (const float*)d_in[4]; gp.C[0] = Qp;  gp.mode[0] = 0;
  gp.A[1] = Kb; gp.Bt[1] = Wkt; gp.bias[1] = (const float*)d_in[6]; gp.C[1] = Kp;  gp.mode[1] = 0;
  gp.A[2] = Vb; gp.Bt[2] = Wvt; gp.bias[2] = (const float*)d_in[8]; gp.C[2] = VpT; gp.mode[2] = 2;
  gp.cpx = 192; gp.zshift = 9;         // BM=64: 512 tiles per z, 1536 blocks = 6/CU
  hipLaunchKernelGGL((gemm_bt<64>), dim3(1536), dim3(256), 0, stream, gp);

  hipLaunchKernelGGL(attn_fwd, dim3(1024), dim3(256), 0, stream, Qp, Kp, VpT, Op);

  GemmB gf;
  gf.A[0] = Op; gf.Bt[0] = Wot; gf.bias[0] = (const float*)d_in[10]; gf.C[0] = (void*)d_out; gf.mode[0] = 1;
  gf.A[1] = nullptr; gf.A[2] = nullptr; gf.Bt[1] = nullptr; gf.Bt[2] = nullptr;
  gf.bias[1] = nullptr; gf.bias[2] = nullptr; gf.C[1] = nullptr; gf.C[2] = nullptr;
  gf.mode[1] = 0; gf.mode[2] = 0;
  gf.cpx = 64; gf.zshift = 9;          // 512 blocks = 2/CU
  hipLaunchKernelGGL((gemm_bt<64>), dim3(512), dim3(256), 0, stream, gf);
}